// Round 14
// baseline (2163.953 us; speedup 1.0000x reference)
//
#include <hip/hip_runtime.h>
#include <hip/hip_bf16.h>

// MSAColumnAttention — R14: R12 numerics (OCML exp2f — already bare v_exp +
// 1 cndmask; R13 proved raw-TRANS -> inline-asm cvtpk is the hazard that broke
// R5/R13). Structural change: attn split into 2 independent 256-thr blocks/CU
// (4 waves each, 72KB LDS) — separate barrier domains drift out of phase so
// one block's exp (VALU) overlaps the other's MFMA (m114 cross-wave co-issue).
//
// 32x32x16 bf16 MFMA layouts (R4/R6-verified):
//   A[m][k]: lane(gg,j)=gg*32+j holds row m=j, k=8gg+e ; B likewise (col n=j)
//   D[m][n]: lane(gg,j) holds col n=j, rows m=(reg&3)+8*(reg>>2)+4*gg
// Fragment construction: 8x cvt_pk + 4x permlane32_swap per D-tile (verified).
//
// ws layout (total 202,117,120 B):
//   Wfrag [8][4][16 kc][64 lane][8 bf16] @0 (512 KB) | ball [1024] f32 @524288
//   oWfh [8 mtile][16 kc][64 lane][8] bf16 @528384 | oWfl @659456
//   xhat [196608][256] bf16 @790528 | obuf [196608][256] bf16 @101453824

#define S_DIM 512
#define R_DIM 384
#define CM    256
#define NH    8
#define NROWS (S_DIM*R_DIM)

typedef unsigned short u16;
typedef unsigned int   u32;
typedef short bf16x8 __attribute__((ext_vector_type(8)));
typedef float f32x4  __attribute__((ext_vector_type(4)));
typedef float f32x16 __attribute__((ext_vector_type(16)));
typedef int   v2i    __attribute__((ext_vector_type(2)));

#define MFMA32(a,b,c) __builtin_amdgcn_mfma_f32_32x32x16_bf16((a),(b),(c),0,0,0)

__device__ __forceinline__ float lo16f(u32 u){ return __uint_as_float(u << 16); }
__device__ __forceinline__ float hi16f(u32 u){ return __uint_as_float(u & 0xffff0000u); }
__device__ __forceinline__ float b2f(u16 x){ return __uint_as_float(((u32)x) << 16); }
__device__ __forceinline__ u16 f2bf(float f){
  u32 u = __float_as_uint(f);
  return (u16)((u + 0x7fffu + ((u >> 16) & 1u)) >> 16);   // RNE
}
__device__ __forceinline__ u32 pk2(float a, float b){
  return (u32)f2bf(a) | ((u32)f2bf(b) << 16);
}
__device__ __forceinline__ u32 cvtpk(float a, float b){
  u32 d;
  asm("v_cvt_pk_bf16_f32 %0, %1, %2" : "=v"(d) : "v"(a), "v"(b));
  return d;
}
__device__ __forceinline__ v2i pl32swap(u32 a, u32 b){
  return __builtin_amdgcn_permlane32_swap((int)a, (int)b, false, false);
}
__device__ __forceinline__ f32x16 zero16(){
  f32x16 z;
  #pragma unroll
  for(int q=0;q<16;q++) z[q]=0.f;
  return z;
}

#define SC2 0.2550348653f   // (1/sqrt(32)) * log2(e), folded into K at prep (R9-proven)

// ---------------------------------------------------------------- prep_w ----
// blocks 0..1023 (h*128 + mat*32 + c): fold ln (and SC2 for K) into W row,
// write FRAG-ORDERED Wfrag[h][mat][kc][lane=gg*32+c][8] bf16; ball likewise.
// blocks 1024..1279: oW hi/lo split, FRAG-ORDERED oWfh/oWfl[mtile][kc][lane][8].
__global__ void prep_w(const float* __restrict__ lnw, const float* __restrict__ lnb,
                       const float* __restrict__ Wq, const float* __restrict__ Wk,
                       const float* __restrict__ Wv, const float* __restrict__ Wg,
                       const float* __restrict__ oW,
                       float* __restrict__ ball, u16* __restrict__ Wfrag,
                       u16* __restrict__ oWfh, u16* __restrict__ oWfl){
  int blk = blockIdx.x, t = threadIdx.x;
  // elements k(d) = 4t..4t+3 -> kc = t>>2, gg = (t>>1)&1, e0 = (t&1)*4
  int kc = t >> 2, gg = (t >> 1) & 1, e0 = (t & 1) * 4;
  if (blk < 1024){
    int h = blk >> 7, row = blk & 127, mat = row >> 5, c = row & 31;
    const float* Ws = (mat==0?Wq: mat==1?Wk: mat==2?Wv:Wg) + (size_t)(h*32+c)*CM;
    const float qs = (mat==1) ? SC2 : 1.f;   // fold softmax scale into K (f32, pre-round)
    float4 w4 = ((const float4*)Ws)[t];
    float4 l4 = ((const float4*)(lnw + (size_t)h*CM))[t];
    float4 b4 = ((const float4*)(lnb + (size_t)h*CM))[t];
    u16* dst = Wfrag + ((size_t)(((blk>>5)*16 + kc))*64 + gg*32 + c)*8 + e0;  // blk>>5 = h*4+mat
    *(uint2*)dst = make_uint2(pk2(qs*w4.x*l4.x, qs*w4.y*l4.y),
                              pk2(qs*w4.z*l4.z, qs*w4.w*l4.w));
    float p = w4.x*b4.x + w4.y*b4.y + w4.z*b4.z + w4.w*b4.w;
    #pragma unroll
    for(int off=32; off; off>>=1) p += __shfl_down(p, off);
    if(t==0) ball[blk] = qs*p;
  } else {
    int m = blk - 1024;
    float4 w4 = ((const float4*)(oW + (size_t)m*CM))[t];
    u16 h0=f2bf(w4.x), h1=f2bf(w4.y), h2=f2bf(w4.z), h3=f2bf(w4.w);
    u16 l0=f2bf(w4.x-b2f(h0)), l1=f2bf(w4.y-b2f(h1));
    u16 l2=f2bf(w4.z-b2f(h2)), l3=f2bf(w4.w-b2f(h3));
    size_t idx = ((size_t)(((m>>5)*16 + kc))*64 + gg*32 + (m&31))*8 + e0;
    *(uint2*)(oWfh + idx) = make_uint2((u32)h0|((u32)h1<<16), (u32)h2|((u32)h3<<16));
    *(uint2*)(oWfl + idx) = make_uint2((u32)l0|((u32)l1<<16), (u32)l2|((u32)l3<<16));
  }
}

// ---------------------------------------------------------------- ln_xhat ----
__global__ __launch_bounds__(256) void ln_xhat(const float* __restrict__ msa,
                                               u16* __restrict__ xhat){
  const int tid = threadIdx.x;
  const int n0 = blockIdx.x*64;
  const int i = tid >> 2, p = tid & 3;
  const int n = n0 + i, rr = n >> 9, s = n & 511;
  const float* src = msa + ((size_t)s*R_DIM + rr)*CM + p*64;
  float x[64]; float sum=0.f, sq=0.f;
  #pragma unroll
  for(int j=0;j<64;j+=4){
    float4 v = *(const float4*)(src + j);
    x[j]=v.x; x[j+1]=v.y; x[j+2]=v.z; x[j+3]=v.w;
    sum += v.x+v.y+v.z+v.w;
    sq  += v.x*v.x + v.y*v.y + v.z*v.z + v.w*v.w;
  }
  sum += __shfl_xor(sum,1); sum += __shfl_xor(sum,2);
  sq  += __shfl_xor(sq,1);  sq  += __shfl_xor(sq,2);
  float mu = sum*(1.f/256.f);
  float rs = rsqrtf(sq*(1.f/256.f) - mu*mu + 1e-5f);
  u16* dst = xhat + (size_t)n*CM + p*64;
  #pragma unroll
  for(int j=0;j<64;j+=2)
    *(u32*)(dst + j) = pk2((x[j]-mu)*rs, (x[j+1]-mu)*rs);
}

// --------------------------------------------------------------- attn_fused7 ----
// 256 thr / 4 waves, 2 blocks/CU (72 KB LDS each; independent barrier domains).
// Wave w owns s-tiles {4w..4w+3}. proj: Wf from Wfrag (L2-hot); Q->regs (Qfr[4][2]),
// K/V->LDS, G->obuf. phase1: per-wave partial d over own 128 s -> dred[4][512];
// reduce -> ivd. V-scale by ivd; phase2: QK+exp+PV per own s-tiles; gate via obuf.
#define KF    0
#define VF    32768
#define DRED  65536
#define ATTN_LDS 73728

__global__ __launch_bounds__(256,2) void attn_fused7(const u16* __restrict__ xhat,
      const u16* __restrict__ Wfrag, const float* __restrict__ ball,
      u16* __restrict__ obuf){
  extern __shared__ char sm[];
  const int bid = blockIdx.x;
  const int xcd = bid & 7, kk2 = bid >> 3;
  const int r = xcd*48 + (kk2 >> 3);     // 8 heads of one r consecutive on one XCD
  const int head = kk2 & 7;
  const int tid  = threadIdx.x;
  const int w    = tid >> 6;             // 0..3
  const int lane = tid & 63;
  const int gg = lane >> 5, j = lane & 31;
  const int n0 = r * 512;

  bf16x8 Qfr[4][2];   // own 4 s-tiles' Q fragments (static indexing only)

  // ================= proj =================
  {
    #pragma unroll
    for(int mat=0; mat<4; mat++){
      bf16x8 Wf[16];
      const u16* wsrc = Wfrag + ((size_t)((head*4+mat)*16)*64 + lane)*8;
      #pragma unroll
      for(int kc=0;kc<16;kc++) Wf[kc] = *(const bf16x8*)(wsrc + (size_t)kc*512);
      float bias16[16]; float biasv = 0.f;
      if (mat == 2) biasv = ball[head*128 + 64 + j];
      else {
        #pragma unroll
        for(int reg=0;reg<16;reg++)
          bias16[reg] = ball[head*128 + mat*32 + (reg&3) + 8*(reg>>2) + 4*gg];
      }
      #pragma unroll
      for(int st=0; st<4; st++){
        const int stg = 4*w + st;
        const u16* xr = xhat + ((size_t)(n0 + stg*32 + j))*CM + gg*8;
        f32x16 D = zero16();
        if (mat == 2){
          #pragma unroll
          for(int kc=0;kc<16;kc++) D = MFMA32(*(const bf16x8*)(xr + kc*16), Wf[kc], D);
        } else {
          #pragma unroll
          for(int kc=0;kc<16;kc++) D = MFMA32(Wf[kc], *(const bf16x8*)(xr + kc*16), D);
        }
        if (mat == 3){                     // G: sigmoid -> obuf (gate staging)
          u32 gw[8];
          #pragma unroll
          for(int p=0;p<4;p++)
            #pragma unroll
            for(int hh=0;hh<2;hh++){
              float a = D[4*p+2*hh]   + bias16[4*p+2*hh];
              float b = D[4*p+2*hh+1] + bias16[4*p+2*hh+1];
              gw[p*2+hh] = cvtpk(1.f/(1.f + __expf(-a)), 1.f/(1.f + __expf(-b)));
            }
          int srow = n0 + stg*32 + j;
          u32* ob32 = (u32*)(obuf + (size_t)srow*CM + head*32);
          #pragma unroll
          for(int p=0;p<4;p++)
            #pragma unroll
            for(int hh=0;hh<2;hh++)
              ob32[4*p + 2*gg + hh] = gw[p*2+hh];
        } else {
          if (mat == 2){
            #pragma unroll
            for(int q=0;q<16;q++) D[q] += biasv;
          } else {
            #pragma unroll
            for(int q=0;q<16;q++) D[q] += bias16[q];
          }
          u32 Wd[8];
          #pragma unroll
          for(int p=0;p<4;p++)
            #pragma unroll
            for(int hh=0;hh<2;hh++)
              Wd[p*2+hh] = cvtpk(D[4*p+2*hh], D[4*p+2*hh+1]);
          u32 frag[2][4];
          #pragma unroll
          for(int T=0;T<2;T++)
            #pragma unroll
            for(int hh=0;hh<2;hh++){
              v2i res = pl32swap(Wd[4*T+hh], Wd[4*T+2+hh]);
              frag[T][hh] = (u32)res[0]; frag[T][2+hh] = (u32)res[1];
            }
          if (mat == 0){
            #pragma unroll
            for(int T=0;T<2;T++){
              union { u32 wu[4]; bf16x8 v; } u;
              u.wu[0]=frag[T][0]; u.wu[1]=frag[T][1]; u.wu[2]=frag[T][2]; u.wu[3]=frag[T][3];
              Qfr[st][T] = u.v;
            }
          } else {
            char* outbase = sm + (mat==1? KF : VF);
            #pragma unroll
            for(int T=0;T<2;T++)
              *(uint4*)(outbase + ((size_t)(stg*2+T)*64 + lane)*16) =
                  make_uint4(frag[T][0],frag[T][1],frag[T][2],frag[T][3]);
          }
        }
      }
    }
  }
  __syncthreads();

  // ================= phase 1: per-wave partial d (own 128 s); reduce -> ivd ===
  {
    float* dred = (float*)(sm + DRED);
    #pragma unroll 2
    for(int tt=0; tt<16; tt++){
      bf16x8 Kt0 = *(const bf16x8*)(sm + KF + ((size_t)(tt*2+0)*64 + lane)*16);
      bf16x8 Kt1 = *(const bf16x8*)(sm + KF + ((size_t)(tt*2+1)*64 + lane)*16);
      float dp = 0.f;
      #pragma unroll
      for(int sb=0; sb<4; sb++){
        f32x16 D1 = zero16();
        D1 = MFMA32(Qfr[sb][0], Kt0, D1);   // D1[s][t] over c (K pre-scaled by SC2)
        D1 = MFMA32(Qfr[sb][1], Kt1, D1);
        #pragma unroll
        for(int q=0;q<16;q++) dp += exp2f(D1[q]);
      }
      v2i rr = pl32swap(__float_as_uint(dp), __float_as_uint(dp));
      float tot = __uint_as_float((u32)rr[0]) + __uint_as_float((u32)rr[1]);
      if (lane < 32) dred[w*512 + tt*32 + j] = tot;
    }
  }
  __syncthreads();
  {
    float* dred = (float*)(sm + DRED);
    #pragma unroll
    for(int half=0; half<2; half++){
      int tix = tid + half*256;
      float s = dred[tix] + dred[512+tix] + dred[1024+tix] + dred[1536+tix];
      dred[tix] = 1.f / s;                  // ivd overlays row 0 (disjoint per thread)
    }
  }
  __syncthreads();

  // ================= scale V-frags by ivd[t] =================
  {
    const float* ivd = (const float*)(sm + DRED);
    #pragma unroll
    for(int it=0; it<8; it++){
      int ch = tid + it*256;
      int t0 = (ch>>7)*32 + ((ch>>6)&1)*16 + ((ch>>5)&1)*8;
      u32* pw = (u32*)(sm + VF + (size_t)ch*16);
      uint4 v = *(uint4*)pw;
      u32 wv[4] = {v.x, v.y, v.z, v.w};
      u32 nw[4];
      #pragma unroll
      for(int rr2=0;rr2<4;rr2++){
        float lo = lo16f(wv[rr2]) * ivd[t0 + 2*rr2];
        float hi = hi16f(wv[rr2]) * ivd[t0 + 2*rr2 + 1];
        nw[rr2] = cvtpk(lo, hi);
      }
      *(uint4*)pw = make_uint4(nw[0],nw[1],nw[2],nw[3]);
    }
  }
  __syncthreads();

  // ================= phase 2 + gated epilogue =================
  #pragma unroll
  for(int sb=0; sb<4; sb++){
    f32x16 O = zero16();
    #pragma unroll 2
    for(int tt=0; tt<16; tt++){
      bf16x8 Kt0 = *(const bf16x8*)(sm + KF + ((size_t)(tt*2+0)*64 + lane)*16);
      bf16x8 Kt1 = *(const bf16x8*)(sm + KF + ((size_t)(tt*2+1)*64 + lane)*16);
      bf16x8 Vt0 = *(const bf16x8*)(sm + VF + ((size_t)(tt*2+0)*64 + lane)*16);
      bf16x8 Vt1 = *(const bf16x8*)(sm + VF + ((size_t)(tt*2+1)*64 + lane)*16);
      f32x16 D = zero16();
      D = MFMA32(Kt0, Qfr[sb][0], D);      // D[t][s] over c (pre-scaled)
      D = MFMA32(Kt1, Qfr[sb][1], D);
      u32 Wd[8];
      #pragma unroll
      for(int p=0;p<4;p++)
        #pragma unroll
        for(int hh=0;hh<2;hh++)
          Wd[p*2+hh] = cvtpk(exp2f(D[4*p+2*hh]), exp2f(D[4*p+2*hh+1]));
      union { u32 wu[4]; bf16x8 v; } pf0, pf1;
      #pragma unroll
      for(int hh=0;hh<2;hh++){
        v2i res = pl32swap(Wd[0+hh], Wd[2+hh]);
        pf0.wu[hh] = (u32)res[0]; pf0.wu[2+hh] = (u32)res[1];
        v2i res2 = pl32swap(Wd[4+hh], Wd[6+hh]);
        pf1.wu[hh] = (u32)res2[0]; pf1.wu[2+hh] = (u32)res2[1];
      }
      O = MFMA32(Vt0, pf0.v, O);
      O = MFMA32(Vt1, pf1.v, O);
    }
    // epilogue: read gate from obuf, multiply, overwrite
    const int stg = 4*w + sb;
    const int srow = n0 + stg*32 + j;
    u32* ob32 = (u32*)(obuf + (size_t)srow*CM + head*32);
    #pragma unroll
    for(int p=0;p<4;p++)
      #pragma unroll
      for(int hh=0;hh<2;hh++){
        u32 gv = ob32[4*p + 2*gg + hh];
        float o0 = O[4*p+2*hh]   * lo16f(gv);
        float o1 = O[4*p+2*hh+1] * hi16f(gv);
        ob32[4*p + 2*gg + hh] = cvtpk(o0, o1);
      }
  }
}

// --------------------------------------------------------------- outproj2 ----
// MFMA32, frag-ordered weights. 256 thr / 4 waves; wave w -> rows row0..row0+31.
__global__ __launch_bounds__(256,4) void outproj2(const u16* __restrict__ obuf,
      const u16* __restrict__ oWfh, const u16* __restrict__ oWfl,
      const float* __restrict__ ob, float* __restrict__ out){
  const int tid = threadIdx.x, w = tid>>6, lane = tid&63;
  const int gg = lane>>5, j = lane&31;
  const int row0 = blockIdx.x*128 + w*32;
  const u16* arow = obuf + (size_t)(row0 + j)*CM + gg*8;
  #pragma unroll 2
  for(int ct=0; ct<8; ct++){
    f32x16 acc = zero16();
    const u16* bh = oWfh + ((size_t)(ct*16)*64 + lane)*8;
    const u16* bl = oWfl + ((size_t)(ct*16)*64 + lane)*8;
    #pragma unroll
    for(int kc=0; kc<16; kc++){
      bf16x8 a = *(const bf16x8*)(arow + kc*16);
      acc = MFMA32(a, *(const bf16x8*)(bh + (size_t)kc*512), acc);
      acc = MFMA32(a, *(const bf16x8*)(bl + (size_t)kc*512), acc);
    }
    float bias = ob[ct*32 + j];
    #pragma unroll
    for(int reg=0; reg<16; reg++){
      int n = row0 + (reg&3) + 8*(reg>>2) + 4*gg;
      out[((size_t)(n & 511)*R_DIM + (n >> 9))*CM + ct*32 + j] = acc[reg] + bias;
    }
  }
}

// ------------------------------------------------------------------ host ----
extern "C" void kernel_launch(void* const* d_in, const int* in_sizes, int n_in,
                              void* d_out, int out_size, void* d_ws, size_t ws_size,
                              hipStream_t stream){
  const float* msa = (const float*)d_in[0];
  const float* lnw = (const float*)d_in[1];
  const float* lnb = (const float*)d_in[2];
  const float* Wq  = (const float*)d_in[3];
  const float* Wk  = (const float*)d_in[4];
  const float* Wv  = (const float*)d_in[5];
  const float* Wg  = (const float*)d_in[6];
  const float* oW  = (const float*)d_in[7];
  const float* ob  = (const float*)d_in[8];
  float* out = (float*)d_out;

  char* ws = (char*)d_ws;
  u16*   Wfrag  = (u16*)(ws);
  float* ball   = (float*)(ws + 524288);
  u16*   oWfh   = (u16*)(ws + 528384);
  u16*   oWfl   = (u16*)(ws + 659456);
  u16*   xhat   = (u16*)(ws + 790528);
  u16*   obuf   = (u16*)(ws + 101453824);

  (void)hipFuncSetAttribute((const void*)attn_fused7,
                      hipFuncAttributeMaxDynamicSharedMemorySize, ATTN_LDS);

  prep_w<<<dim3(1280), dim3(64), 0, stream>>>(lnw, lnb, Wq, Wk, Wv, Wg, oW,
                                              ball, Wfrag, oWfh, oWfl);
  ln_xhat<<<dim3(NROWS/64), dim3(256), 0, stream>>>(msa, xhat);
  attn_fused7<<<dim3(R_DIM*NH), dim3(256), ATTN_LDS, stream>>>(xhat, Wfrag, ball, obuf);
  outproj2<<<dim3(NROWS/128), dim3(256), 0, stream>>>(obuf, oWfh, oWfl, ob, out);
}

// Round 15
// 1056.206 us; speedup vs baseline: 2.0488x; 2.0488x over previous
//
#include <hip/hip_runtime.h>
#include <hip/hip_bf16.h>

// MSAColumnAttention — R15: R12 (best verified: 1013us total, attn 705us)
// + gate G staged in padded LDS instead of a global obuf round-trip.
// R14 post-mortem settled the model: ~256 unified regs/wave -> 2 waves/SIMD
// is a hard wall (5 failed structural attempts); optimize within it.
// G: [512 rows][17 u32] (68B row pitch, stride 17 coprime 32 -> conflict-free).
//
// 32x32x16 bf16 MFMA layouts (R4/R6-verified):
//   A[m][k]: lane(gg,j)=gg*32+j holds row m=j, k=8gg+e ; B likewise (col n=j)
//   D[m][n]: lane(gg,j) holds col n=j, rows m=(reg&3)+8*(reg>>2)+4*gg
// Fragment construction: 8x cvt_pk + 4x permlane32_swap per D-tile (verified).
//
// ws layout (total 202,117,120 B):
//   Wfrag [8][4][16 kc][64 lane][8 bf16] @0 (512 KB) | ball [1024] f32 @524288
//   oWfh [8 mtile][16 kc][64 lane][8] bf16 @528384 | oWfl @659456
//   xhat [196608][256] bf16 @790528 | obuf [196608][256] bf16 @101453824

#define S_DIM 512
#define R_DIM 384
#define CM    256
#define NH    8
#define NROWS (S_DIM*R_DIM)

typedef unsigned short u16;
typedef unsigned int   u32;
typedef short bf16x8 __attribute__((ext_vector_type(8)));
typedef float f32x4  __attribute__((ext_vector_type(4)));
typedef float f32x16 __attribute__((ext_vector_type(16)));
typedef int   v2i    __attribute__((ext_vector_type(2)));

#define MFMA32(a,b,c) __builtin_amdgcn_mfma_f32_32x32x16_bf16((a),(b),(c),0,0,0)

__device__ __forceinline__ float lo16f(u32 u){ return __uint_as_float(u << 16); }
__device__ __forceinline__ float hi16f(u32 u){ return __uint_as_float(u & 0xffff0000u); }
__device__ __forceinline__ float b2f(u16 x){ return __uint_as_float(((u32)x) << 16); }
__device__ __forceinline__ u16 f2bf(float f){
  u32 u = __float_as_uint(f);
  return (u16)((u + 0x7fffu + ((u >> 16) & 1u)) >> 16);   // RNE
}
__device__ __forceinline__ u32 pk2(float a, float b){
  return (u32)f2bf(a) | ((u32)f2bf(b) << 16);
}
__device__ __forceinline__ u32 cvtpk(float a, float b){
  u32 d;
  asm("v_cvt_pk_bf16_f32 %0, %1, %2" : "=v"(d) : "v"(a), "v"(b));
  return d;
}
__device__ __forceinline__ v2i pl32swap(u32 a, u32 b){
  return __builtin_amdgcn_permlane32_swap((int)a, (int)b, false, false);
}
__device__ __forceinline__ f32x16 zero16(){
  f32x16 z;
  #pragma unroll
  for(int q=0;q<16;q++) z[q]=0.f;
  return z;
}

#define SC2 0.2550348653f   // (1/sqrt(32)) * log2(e), folded into K at prep (R9-proven)

// ---------------------------------------------------------------- prep_w ----
// blocks 0..1023 (h*128 + mat*32 + c): fold ln (and SC2 for K) into W row,
// write FRAG-ORDERED Wfrag[h][mat][kc][lane=gg*32+c][8] bf16; ball likewise.
// blocks 1024..1279: oW hi/lo split, FRAG-ORDERED oWfh/oWfl[mtile][kc][lane][8].
__global__ void prep_w(const float* __restrict__ lnw, const float* __restrict__ lnb,
                       const float* __restrict__ Wq, const float* __restrict__ Wk,
                       const float* __restrict__ Wv, const float* __restrict__ Wg,
                       const float* __restrict__ oW,
                       float* __restrict__ ball, u16* __restrict__ Wfrag,
                       u16* __restrict__ oWfh, u16* __restrict__ oWfl){
  int blk = blockIdx.x, t = threadIdx.x;
  // elements k(d) = 4t..4t+3 -> kc = t>>2, gg = (t>>1)&1, e0 = (t&1)*4
  int kc = t >> 2, gg = (t >> 1) & 1, e0 = (t & 1) * 4;
  if (blk < 1024){
    int h = blk >> 7, row = blk & 127, mat = row >> 5, c = row & 31;
    const float* Ws = (mat==0?Wq: mat==1?Wk: mat==2?Wv:Wg) + (size_t)(h*32+c)*CM;
    const float qs = (mat==1) ? SC2 : 1.f;   // fold softmax scale into K (f32, pre-round)
    float4 w4 = ((const float4*)Ws)[t];
    float4 l4 = ((const float4*)(lnw + (size_t)h*CM))[t];
    float4 b4 = ((const float4*)(lnb + (size_t)h*CM))[t];
    u16* dst = Wfrag + ((size_t)(((blk>>5)*16 + kc))*64 + gg*32 + c)*8 + e0;  // blk>>5 = h*4+mat
    *(uint2*)dst = make_uint2(pk2(qs*w4.x*l4.x, qs*w4.y*l4.y),
                              pk2(qs*w4.z*l4.z, qs*w4.w*l4.w));
    float p = w4.x*b4.x + w4.y*b4.y + w4.z*b4.z + w4.w*b4.w;
    #pragma unroll
    for(int off=32; off; off>>=1) p += __shfl_down(p, off);
    if(t==0) ball[blk] = qs*p;
  } else {
    int m = blk - 1024;
    float4 w4 = ((const float4*)(oW + (size_t)m*CM))[t];
    u16 h0=f2bf(w4.x), h1=f2bf(w4.y), h2=f2bf(w4.z), h3=f2bf(w4.w);
    u16 l0=f2bf(w4.x-b2f(h0)), l1=f2bf(w4.y-b2f(h1));
    u16 l2=f2bf(w4.z-b2f(h2)), l3=f2bf(w4.w-b2f(h3));
    size_t idx = ((size_t)(((m>>5)*16 + kc))*64 + gg*32 + (m&31))*8 + e0;
    *(uint2*)(oWfh + idx) = make_uint2((u32)h0|((u32)h1<<16), (u32)h2|((u32)h3<<16));
    *(uint2*)(oWfl + idx) = make_uint2((u32)l0|((u32)l1<<16), (u32)l2|((u32)l3<<16));
  }
}

// ---------------------------------------------------------------- ln_xhat ----
__global__ __launch_bounds__(256) void ln_xhat(const float* __restrict__ msa,
                                               u16* __restrict__ xhat){
  const int tid = threadIdx.x;
  const int n0 = blockIdx.x*64;
  const int i = tid >> 2, p = tid & 3;
  const int n = n0 + i, rr = n >> 9, s = n & 511;
  const float* src = msa + ((size_t)s*R_DIM + rr)*CM + p*64;
  float x[64]; float sum=0.f, sq=0.f;
  #pragma unroll
  for(int j=0;j<64;j+=4){
    float4 v = *(const float4*)(src + j);
    x[j]=v.x; x[j+1]=v.y; x[j+2]=v.z; x[j+3]=v.w;
    sum += v.x+v.y+v.z+v.w;
    sq  += v.x*v.x + v.y*v.y + v.z*v.z + v.w*v.w;
  }
  sum += __shfl_xor(sum,1); sum += __shfl_xor(sum,2);
  sq  += __shfl_xor(sq,1);  sq  += __shfl_xor(sq,2);
  float mu = sum*(1.f/256.f);
  float rs = rsqrtf(sq*(1.f/256.f) - mu*mu + 1e-5f);
  u16* dst = xhat + (size_t)n*CM + p*64;
  #pragma unroll
  for(int j=0;j<64;j+=2)
    *(u32*)(dst + j) = pk2((x[j]-mu)*rs, (x[j+1]-mu)*rs);
}

// --------------------------------------------------------------- attn_fused4 ----
// 512 thr / 8 waves, 1 block/CU (LDS-capped). Wave w owns s-tiles {2w, 2w+1}.
// proj: Wf from Wfrag (L2-hot); Q->regs, K/V->LDS, G->LDS (padded rows).
// phase1: per-wave partial d -> dred; reduce -> ivd. V-scale by ivd;
// phase2: QK+exp+PV per own s-tile; epilogue gates from LDS, pure store to obuf.
#define KF    0
#define VF    32768
#define DRED  65536
#define GF    81920                  // [512 rows][17 u32] = 34816 B (pad: 17%32 coprime)
#define ATTN_LDS 116736

__global__ __launch_bounds__(512,1) void attn_fused4(const u16* __restrict__ xhat,
      const u16* __restrict__ Wfrag, const float* __restrict__ ball,
      u16* __restrict__ obuf){
  extern __shared__ char sm[];
  const int bid = blockIdx.x;
  const int xcd = bid & 7, kk2 = bid >> 3;
  const int r = xcd*48 + (kk2 >> 3);     // 8 heads of one r consecutive on one XCD
  const int head = kk2 & 7;
  const int tid  = threadIdx.x;
  const int w    = tid >> 6;
  const int lane = tid & 63;
  const int gg = lane >> 5, j = lane & 31;
  const int n0 = r * 512;

  bf16x8 Qfr[2][2];   // own s-tiles' Q fragments (static indexing only)

  // ================= proj =================
  {
    #pragma unroll
    for(int mat=0; mat<4; mat++){
      bf16x8 Wf[16];
      const u16* wsrc = Wfrag + ((size_t)((head*4+mat)*16)*64 + lane)*8;
      #pragma unroll
      for(int kc=0;kc<16;kc++) Wf[kc] = *(const bf16x8*)(wsrc + (size_t)kc*512);
      float bias16[16]; float biasv = 0.f;
      if (mat == 2) biasv = ball[head*128 + 64 + j];
      else {
        #pragma unroll
        for(int reg=0;reg<16;reg++)
          bias16[reg] = ball[head*128 + mat*32 + (reg&3) + 8*(reg>>2) + 4*gg];
      }
      #pragma unroll
      for(int st=0; st<2; st++){
        const int stg = 2*w + st;
        const u16* xr = xhat + ((size_t)(n0 + stg*32 + j))*CM + gg*8;
        f32x16 D = zero16();
        if (mat == 2){
          #pragma unroll
          for(int kc=0;kc<16;kc++) D = MFMA32(*(const bf16x8*)(xr + kc*16), Wf[kc], D);
        } else {
          #pragma unroll
          for(int kc=0;kc<16;kc++) D = MFMA32(Wf[kc], *(const bf16x8*)(xr + kc*16), D);
        }
        if (mat == 3){                     // G: sigmoid -> LDS (padded rows)
          char* grow = sm + GF + (size_t)(stg*32 + j)*68;
          #pragma unroll
          for(int p=0;p<4;p++)
            #pragma unroll
            for(int hh=0;hh<2;hh++){
              float a = D[4*p+2*hh]   + bias16[4*p+2*hh];
              float b = D[4*p+2*hh+1] + bias16[4*p+2*hh+1];
              *(u32*)(grow + (4*p + 2*gg + hh)*4) =
                  cvtpk(1.f/(1.f + __expf(-a)), 1.f/(1.f + __expf(-b)));
            }
        } else {
          if (mat == 2){
            #pragma unroll
            for(int q=0;q<16;q++) D[q] += biasv;
          } else {
            #pragma unroll
            for(int q=0;q<16;q++) D[q] += bias16[q];
          }
          u32 Wd[8];
          #pragma unroll
          for(int p=0;p<4;p++)
            #pragma unroll
            for(int hh=0;hh<2;hh++)
              Wd[p*2+hh] = cvtpk(D[4*p+2*hh], D[4*p+2*hh+1]);
          u32 frag[2][4];
          #pragma unroll
          for(int T=0;T<2;T++)
            #pragma unroll
            for(int hh=0;hh<2;hh++){
              v2i res = pl32swap(Wd[4*T+hh], Wd[4*T+2+hh]);
              frag[T][hh] = (u32)res[0]; frag[T][2+hh] = (u32)res[1];
            }
          if (mat == 0){
            #pragma unroll
            for(int T=0;T<2;T++){
              union { u32 wu[4]; bf16x8 v; } u;
              u.wu[0]=frag[T][0]; u.wu[1]=frag[T][1]; u.wu[2]=frag[T][2]; u.wu[3]=frag[T][3];
              Qfr[st][T] = u.v;
            }
          } else {
            char* outbase = sm + (mat==1? KF : VF);
            #pragma unroll
            for(int T=0;T<2;T++)
              *(uint4*)(outbase + ((size_t)(stg*2+T)*64 + lane)*16) =
                  make_uint4(frag[T][0],frag[T][1],frag[T][2],frag[T][3]);
          }
        }
      }
    }
  }
  __syncthreads();

  // ================= phase 1: per-wave partial d; reduce -> ivd =========
  {
    float* dred = (float*)(sm + DRED);
    #pragma unroll 2
    for(int tt=0; tt<16; tt++){
      bf16x8 Kt0 = *(const bf16x8*)(sm + KF + ((size_t)(tt*2+0)*64 + lane)*16);
      bf16x8 Kt1 = *(const bf16x8*)(sm + KF + ((size_t)(tt*2+1)*64 + lane)*16);
      float dp = 0.f;
      #pragma unroll
      for(int sb=0; sb<2; sb++){
        f32x16 D1 = zero16();
        D1 = MFMA32(Qfr[sb][0], Kt0, D1);   // D1[s][t] over c (K pre-scaled by SC2)
        D1 = MFMA32(Qfr[sb][1], Kt1, D1);
        #pragma unroll
        for(int q=0;q<16;q++) dp += exp2f(D1[q]);
      }
      v2i rr = pl32swap(__float_as_uint(dp), __float_as_uint(dp));
      float tot = __uint_as_float((u32)rr[0]) + __uint_as_float((u32)rr[1]);
      if (lane < 32) dred[w*512 + tt*32 + j] = tot;
    }
  }
  __syncthreads();
  {
    float* dred = (float*)(sm + DRED);
    float s = 0.f;
    #pragma unroll
    for(int ww=0; ww<8; ww++) s += dred[ww*512 + tid];
    dred[tid] = 1.f / s;                    // ivd overlays row 0
  }
  __syncthreads();

  // ================= scale V-frags by ivd[t] =================
  {
    const float* ivd = (const float*)(sm + DRED);
    #pragma unroll
    for(int it=0; it<4; it++){
      int ch = tid + it*512;
      int t0 = (ch>>7)*32 + ((ch>>6)&1)*16 + ((ch>>5)&1)*8;
      u32* pw = (u32*)(sm + VF + (size_t)ch*16);
      uint4 v = *(uint4*)pw;
      u32 wv[4] = {v.x, v.y, v.z, v.w};
      u32 nw[4];
      #pragma unroll
      for(int rr2=0;rr2<4;rr2++){
        float lo = lo16f(wv[rr2]) * ivd[t0 + 2*rr2];
        float hi = hi16f(wv[rr2]) * ivd[t0 + 2*rr2 + 1];
        nw[rr2] = cvtpk(lo, hi);
      }
      *(uint4*)pw = make_uint4(nw[0],nw[1],nw[2],nw[3]);
    }
  }
  __syncthreads();

  // ================= phase 2 + gated epilogue =================
  #pragma unroll
  for(int sb=0; sb<2; sb++){
    f32x16 O = zero16();
    #pragma unroll 2
    for(int tt=0; tt<16; tt++){
      bf16x8 Kt0 = *(const bf16x8*)(sm + KF + ((size_t)(tt*2+0)*64 + lane)*16);
      bf16x8 Kt1 = *(const bf16x8*)(sm + KF + ((size_t)(tt*2+1)*64 + lane)*16);
      bf16x8 Vt0 = *(const bf16x8*)(sm + VF + ((size_t)(tt*2+0)*64 + lane)*16);
      bf16x8 Vt1 = *(const bf16x8*)(sm + VF + ((size_t)(tt*2+1)*64 + lane)*16);
      f32x16 D = zero16();
      D = MFMA32(Kt0, Qfr[sb][0], D);      // D[t][s] over c (pre-scaled)
      D = MFMA32(Kt1, Qfr[sb][1], D);
      u32 Wd[8];
      #pragma unroll
      for(int p=0;p<4;p++)
        #pragma unroll
        for(int hh=0;hh<2;hh++)
          Wd[p*2+hh] = cvtpk(exp2f(D[4*p+2*hh]), exp2f(D[4*p+2*hh+1]));
      union { u32 wu[4]; bf16x8 v; } pf0, pf1;
      #pragma unroll
      for(int hh=0;hh<2;hh++){
        v2i res = pl32swap(Wd[0+hh], Wd[2+hh]);
        pf0.wu[hh] = (u32)res[0]; pf0.wu[2+hh] = (u32)res[1];
        v2i res2 = pl32swap(Wd[4+hh], Wd[6+hh]);
        pf1.wu[hh] = (u32)res2[0]; pf1.wu[2+hh] = (u32)res2[1];
      }
      O = MFMA32(Vt0, pf0.v, O);
      O = MFMA32(Vt1, pf1.v, O);
    }
    // epilogue: gate from LDS, pure coalesced store to obuf
    const int stg = 2*w + sb;
    const int srow = n0 + stg*32 + j;
    const char* grow = sm + GF + (size_t)(stg*32 + j)*68;
    u32* ob32 = (u32*)(obuf + (size_t)srow*CM + head*32);
    #pragma unroll
    for(int p=0;p<4;p++)
      #pragma unroll
      for(int hh=0;hh<2;hh++){
        u32 gv = *(const u32*)(grow + (4*p + 2*gg + hh)*4);
        float o0 = O[4*p+2*hh]   * lo16f(gv);
        float o1 = O[4*p+2*hh+1] * hi16f(gv);
        ob32[4*p + 2*gg + hh] = cvtpk(o0, o1);
      }
  }
}

// --------------------------------------------------------------- outproj2 ----
// MFMA32, frag-ordered weights. 256 thr / 4 waves; wave w -> rows row0..row0+31.
__global__ __launch_bounds__(256,4) void outproj2(const u16* __restrict__ obuf,
      const u16* __restrict__ oWfh, const u16* __restrict__ oWfl,
      const float* __restrict__ ob, float* __restrict__ out){
  const int tid = threadIdx.x, w = tid>>6, lane = tid&63;
  const int gg = lane>>5, j = lane&31;
  const int row0 = blockIdx.x*128 + w*32;
  const u16* arow = obuf + (size_t)(row0 + j)*CM + gg*8;
  #pragma unroll 2
  for(int ct=0; ct<8; ct++){
    f32x16 acc = zero16();
    const u16* bh = oWfh + ((size_t)(ct*16)*64 + lane)*8;
    const u16* bl = oWfl + ((size_t)(ct*16)*64 + lane)*8;
    #pragma unroll
    for(int kc=0; kc<16; kc++){
      bf16x8 a = *(const bf16x8*)(arow + kc*16);
      acc = MFMA32(a, *(const bf16x8*)(bh + (size_t)kc*512), acc);
      acc = MFMA32(a, *(const bf16x8*)(bl + (size_t)kc*512), acc);
    }
    float bias = ob[ct*32 + j];
    #pragma unroll
    for(int reg=0; reg<16; reg++){
      int n = row0 + (reg&3) + 8*(reg>>2) + 4*gg;
      out[((size_t)(n & 511)*R_DIM + (n >> 9))*CM + ct*32 + j] = acc[reg] + bias;
    }
  }
}

// ------------------------------------------------------------------ host ----
extern "C" void kernel_launch(void* const* d_in, const int* in_sizes, int n_in,
                              void* d_out, int out_size, void* d_ws, size_t ws_size,
                              hipStream_t stream){
  const float* msa = (const float*)d_in[0];
  const float* lnw = (const float*)d_in[1];
  const float* lnb = (const float*)d_in[2];
  const float* Wq  = (const float*)d_in[3];
  const float* Wk  = (const float*)d_in[4];
  const float* Wv  = (const float*)d_in[5];
  const float* Wg  = (const float*)d_in[6];
  const float* oW  = (const float*)d_in[7];
  const float* ob  = (const float*)d_in[8];
  float* out = (float*)d_out;

  char* ws = (char*)d_ws;
  u16*   Wfrag  = (u16*)(ws);
  float* ball   = (float*)(ws + 524288);
  u16*   oWfh   = (u16*)(ws + 528384);
  u16*   oWfl   = (u16*)(ws + 659456);
  u16*   xhat   = (u16*)(ws + 790528);
  u16*   obuf   = (u16*)(ws + 101453824);

  (void)hipFuncSetAttribute((const void*)attn_fused4,
                      hipFuncAttributeMaxDynamicSharedMemorySize, ATTN_LDS);

  prep_w<<<dim3(1280), dim3(64), 0, stream>>>(lnw, lnb, Wq, Wk, Wv, Wg, oW,
                                              ball, Wfrag, oWfh, oWfl);
  ln_xhat<<<dim3(NROWS/64), dim3(256), 0, stream>>>(msa, xhat);
  attn_fused4<<<dim3(R_DIM*NH), dim3(512), ATTN_LDS, stream>>>(xhat, Wfrag, ball, obuf);
  outproj2<<<dim3(NROWS/128), dim3(256), 0, stream>>>(obuf, oWfh, oWfl, ob, out);
}

// Round 16
// 1041.328 us; speedup vs baseline: 2.0781x; 1.0143x over previous
//
#include <hip/hip_runtime.h>
#include <hip/hip_bf16.h>

// MSAColumnAttention — R16: R12 base (best verified 1013us; R15's LDS-G reverted
// — L2 round-trip was cheaper than scattered ds ops). Phase-2 restructured:
// both sb chains interleaved in ONE tt loop (R12's unroll-2 lever applied to
// the orthogonal axis — the two independent O-accumulator chains now overlap).
// Arithmetic identical, just reordered across independent data.
//
// 32x32x16 bf16 MFMA layouts (R4/R6-verified):
//   A[m][k]: lane(gg,j)=gg*32+j holds row m=j, k=8gg+e ; B likewise (col n=j)
//   D[m][n]: lane(gg,j) holds col n=j, rows m=(reg&3)+8*(reg>>2)+4*gg
// Fragment construction: 8x cvt_pk + 4x permlane32_swap per D-tile (verified).
//
// ws layout (total 202,117,120 B):
//   Wfrag [8][4][16 kc][64 lane][8 bf16] @0 (512 KB) | ball [1024] f32 @524288
//   oWfh [8 mtile][16 kc][64 lane][8] bf16 @528384 | oWfl @659456
//   xhat [196608][256] bf16 @790528 | obuf [196608][256] bf16 @101453824

#define S_DIM 512
#define R_DIM 384
#define CM    256
#define NH    8
#define NROWS (S_DIM*R_DIM)

typedef unsigned short u16;
typedef unsigned int   u32;
typedef short bf16x8 __attribute__((ext_vector_type(8)));
typedef float f32x4  __attribute__((ext_vector_type(4)));
typedef float f32x16 __attribute__((ext_vector_type(16)));
typedef int   v2i    __attribute__((ext_vector_type(2)));

#define MFMA32(a,b,c) __builtin_amdgcn_mfma_f32_32x32x16_bf16((a),(b),(c),0,0,0)

__device__ __forceinline__ float lo16f(u32 u){ return __uint_as_float(u << 16); }
__device__ __forceinline__ float hi16f(u32 u){ return __uint_as_float(u & 0xffff0000u); }
__device__ __forceinline__ float b2f(u16 x){ return __uint_as_float(((u32)x) << 16); }
__device__ __forceinline__ u16 f2bf(float f){
  u32 u = __float_as_uint(f);
  return (u16)((u + 0x7fffu + ((u >> 16) & 1u)) >> 16);   // RNE
}
__device__ __forceinline__ u32 pk2(float a, float b){
  return (u32)f2bf(a) | ((u32)f2bf(b) << 16);
}
__device__ __forceinline__ u32 cvtpk(float a, float b){
  u32 d;
  asm("v_cvt_pk_bf16_f32 %0, %1, %2" : "=v"(d) : "v"(a), "v"(b));
  return d;
}
__device__ __forceinline__ v2i pl32swap(u32 a, u32 b){
  return __builtin_amdgcn_permlane32_swap((int)a, (int)b, false, false);
}
__device__ __forceinline__ f32x16 zero16(){
  f32x16 z;
  #pragma unroll
  for(int q=0;q<16;q++) z[q]=0.f;
  return z;
}

#define SC2 0.2550348653f   // (1/sqrt(32)) * log2(e), folded into K at prep (R9-proven)

// ---------------------------------------------------------------- prep_w ----
// blocks 0..1023 (h*128 + mat*32 + c): fold ln (and SC2 for K) into W row,
// write FRAG-ORDERED Wfrag[h][mat][kc][lane=gg*32+c][8] bf16; ball likewise.
// blocks 1024..1279: oW hi/lo split, FRAG-ORDERED oWfh/oWfl[mtile][kc][lane][8].
__global__ void prep_w(const float* __restrict__ lnw, const float* __restrict__ lnb,
                       const float* __restrict__ Wq, const float* __restrict__ Wk,
                       const float* __restrict__ Wv, const float* __restrict__ Wg,
                       const float* __restrict__ oW,
                       float* __restrict__ ball, u16* __restrict__ Wfrag,
                       u16* __restrict__ oWfh, u16* __restrict__ oWfl){
  int blk = blockIdx.x, t = threadIdx.x;
  // elements k(d) = 4t..4t+3 -> kc = t>>2, gg = (t>>1)&1, e0 = (t&1)*4
  int kc = t >> 2, gg = (t >> 1) & 1, e0 = (t & 1) * 4;
  if (blk < 1024){
    int h = blk >> 7, row = blk & 127, mat = row >> 5, c = row & 31;
    const float* Ws = (mat==0?Wq: mat==1?Wk: mat==2?Wv:Wg) + (size_t)(h*32+c)*CM;
    const float qs = (mat==1) ? SC2 : 1.f;   // fold softmax scale into K (f32, pre-round)
    float4 w4 = ((const float4*)Ws)[t];
    float4 l4 = ((const float4*)(lnw + (size_t)h*CM))[t];
    float4 b4 = ((const float4*)(lnb + (size_t)h*CM))[t];
    u16* dst = Wfrag + ((size_t)(((blk>>5)*16 + kc))*64 + gg*32 + c)*8 + e0;  // blk>>5 = h*4+mat
    *(uint2*)dst = make_uint2(pk2(qs*w4.x*l4.x, qs*w4.y*l4.y),
                              pk2(qs*w4.z*l4.z, qs*w4.w*l4.w));
    float p = w4.x*b4.x + w4.y*b4.y + w4.z*b4.z + w4.w*b4.w;
    #pragma unroll
    for(int off=32; off; off>>=1) p += __shfl_down(p, off);
    if(t==0) ball[blk] = qs*p;
  } else {
    int m = blk - 1024;
    float4 w4 = ((const float4*)(oW + (size_t)m*CM))[t];
    u16 h0=f2bf(w4.x), h1=f2bf(w4.y), h2=f2bf(w4.z), h3=f2bf(w4.w);
    u16 l0=f2bf(w4.x-b2f(h0)), l1=f2bf(w4.y-b2f(h1));
    u16 l2=f2bf(w4.z-b2f(h2)), l3=f2bf(w4.w-b2f(h3));
    size_t idx = ((size_t)(((m>>5)*16 + kc))*64 + gg*32 + (m&31))*8 + e0;
    *(uint2*)(oWfh + idx) = make_uint2((u32)h0|((u32)h1<<16), (u32)h2|((u32)h3<<16));
    *(uint2*)(oWfl + idx) = make_uint2((u32)l0|((u32)l1<<16), (u32)l2|((u32)l3<<16));
  }
}

// ---------------------------------------------------------------- ln_xhat ----
__global__ __launch_bounds__(256) void ln_xhat(const float* __restrict__ msa,
                                               u16* __restrict__ xhat){
  const int tid = threadIdx.x;
  const int n0 = blockIdx.x*64;
  const int i = tid >> 2, p = tid & 3;
  const int n = n0 + i, rr = n >> 9, s = n & 511;
  const float* src = msa + ((size_t)s*R_DIM + rr)*CM + p*64;
  float x[64]; float sum=0.f, sq=0.f;
  #pragma unroll
  for(int j=0;j<64;j+=4){
    float4 v = *(const float4*)(src + j);
    x[j]=v.x; x[j+1]=v.y; x[j+2]=v.z; x[j+3]=v.w;
    sum += v.x+v.y+v.z+v.w;
    sq  += v.x*v.x + v.y*v.y + v.z*v.z + v.w*v.w;
  }
  sum += __shfl_xor(sum,1); sum += __shfl_xor(sum,2);
  sq  += __shfl_xor(sq,1);  sq  += __shfl_xor(sq,2);
  float mu = sum*(1.f/256.f);
  float rs = rsqrtf(sq*(1.f/256.f) - mu*mu + 1e-5f);
  u16* dst = xhat + (size_t)n*CM + p*64;
  #pragma unroll
  for(int j=0;j<64;j+=2)
    *(u32*)(dst + j) = pk2((x[j]-mu)*rs, (x[j+1]-mu)*rs);
}

// --------------------------------------------------------------- attn_fused4 ----
// 512 thr / 8 waves, 1 block/CU (LDS-capped). Wave w owns s-tiles {2w, 2w+1}.
// proj: Wf from Wfrag (L2-hot); Q->regs, K/V->LDS, G->obuf.
// phase1: per-wave partial d -> dred; reduce -> ivd. V-scale by ivd;
// phase2: ONE tt loop, both sb chains interleaved (2 indep O chains in flight).
#define KF    0
#define VF    32768
#define DRED  65536
#define ATTN_LDS 81920

__global__ __launch_bounds__(512,1) void attn_fused4(const u16* __restrict__ xhat,
      const u16* __restrict__ Wfrag, const float* __restrict__ ball,
      u16* __restrict__ obuf){
  extern __shared__ char sm[];
  const int bid = blockIdx.x;
  const int xcd = bid & 7, kk2 = bid >> 3;
  const int r = xcd*48 + (kk2 >> 3);     // 8 heads of one r consecutive on one XCD
  const int head = kk2 & 7;
  const int tid  = threadIdx.x;
  const int w    = tid >> 6;
  const int lane = tid & 63;
  const int gg = lane >> 5, j = lane & 31;
  const int n0 = r * 512;

  bf16x8 Qfr[2][2];   // own s-tiles' Q fragments (static indexing only)

  // ================= proj =================
  {
    #pragma unroll
    for(int mat=0; mat<4; mat++){
      bf16x8 Wf[16];
      const u16* wsrc = Wfrag + ((size_t)((head*4+mat)*16)*64 + lane)*8;
      #pragma unroll
      for(int kc=0;kc<16;kc++) Wf[kc] = *(const bf16x8*)(wsrc + (size_t)kc*512);
      float bias16[16]; float biasv = 0.f;
      if (mat == 2) biasv = ball[head*128 + 64 + j];
      else {
        #pragma unroll
        for(int reg=0;reg<16;reg++)
          bias16[reg] = ball[head*128 + mat*32 + (reg&3) + 8*(reg>>2) + 4*gg];
      }
      #pragma unroll
      for(int st=0; st<2; st++){
        const int stg = 2*w + st;
        const u16* xr = xhat + ((size_t)(n0 + stg*32 + j))*CM + gg*8;
        f32x16 D = zero16();
        if (mat == 2){
          #pragma unroll
          for(int kc=0;kc<16;kc++) D = MFMA32(*(const bf16x8*)(xr + kc*16), Wf[kc], D);
        } else {
          #pragma unroll
          for(int kc=0;kc<16;kc++) D = MFMA32(Wf[kc], *(const bf16x8*)(xr + kc*16), D);
        }
        if (mat == 3){                     // G: sigmoid -> obuf (gate staging)
          u32 gw[8];
          #pragma unroll
          for(int p=0;p<4;p++)
            #pragma unroll
            for(int hh=0;hh<2;hh++){
              float a = D[4*p+2*hh]   + bias16[4*p+2*hh];
              float b = D[4*p+2*hh+1] + bias16[4*p+2*hh+1];
              gw[p*2+hh] = cvtpk(1.f/(1.f + __expf(-a)), 1.f/(1.f + __expf(-b)));
            }
          int srow = n0 + stg*32 + j;
          u32* ob32 = (u32*)(obuf + (size_t)srow*CM + head*32);
          #pragma unroll
          for(int p=0;p<4;p++)
            #pragma unroll
            for(int hh=0;hh<2;hh++)
              ob32[4*p + 2*gg + hh] = gw[p*2+hh];
        } else {
          if (mat == 2){
            #pragma unroll
            for(int q=0;q<16;q++) D[q] += biasv;
          } else {
            #pragma unroll
            for(int q=0;q<16;q++) D[q] += bias16[q];
          }
          u32 Wd[8];
          #pragma unroll
          for(int p=0;p<4;p++)
            #pragma unroll
            for(int hh=0;hh<2;hh++)
              Wd[p*2+hh] = cvtpk(D[4*p+2*hh], D[4*p+2*hh+1]);
          u32 frag[2][4];
          #pragma unroll
          for(int T=0;T<2;T++)
            #pragma unroll
            for(int hh=0;hh<2;hh++){
              v2i res = pl32swap(Wd[4*T+hh], Wd[4*T+2+hh]);
              frag[T][hh] = (u32)res[0]; frag[T][2+hh] = (u32)res[1];
            }
          if (mat == 0){
            #pragma unroll
            for(int T=0;T<2;T++){
              union { u32 wu[4]; bf16x8 v; } u;
              u.wu[0]=frag[T][0]; u.wu[1]=frag[T][1]; u.wu[2]=frag[T][2]; u.wu[3]=frag[T][3];
              Qfr[st][T] = u.v;
            }
          } else {
            char* outbase = sm + (mat==1? KF : VF);
            #pragma unroll
            for(int T=0;T<2;T++)
              *(uint4*)(outbase + ((size_t)(stg*2+T)*64 + lane)*16) =
                  make_uint4(frag[T][0],frag[T][1],frag[T][2],frag[T][3]);
          }
        }
      }
    }
  }
  __syncthreads();

  // ================= phase 1: per-wave partial d; reduce -> ivd =========
  {
    float* dred = (float*)(sm + DRED);
    #pragma unroll 2
    for(int tt=0; tt<16; tt++){
      bf16x8 Kt0 = *(const bf16x8*)(sm + KF + ((size_t)(tt*2+0)*64 + lane)*16);
      bf16x8 Kt1 = *(const bf16x8*)(sm + KF + ((size_t)(tt*2+1)*64 + lane)*16);
      float dp = 0.f;
      #pragma unroll
      for(int sb=0; sb<2; sb++){
        f32x16 D1 = zero16();
        D1 = MFMA32(Qfr[sb][0], Kt0, D1);   // D1[s][t] over c (K pre-scaled by SC2)
        D1 = MFMA32(Qfr[sb][1], Kt1, D1);
        #pragma unroll
        for(int q=0;q<16;q++) dp += exp2f(D1[q]);
      }
      v2i rr = pl32swap(__float_as_uint(dp), __float_as_uint(dp));
      float tot = __uint_as_float((u32)rr[0]) + __uint_as_float((u32)rr[1]);
      if (lane < 32) dred[w*512 + tt*32 + j] = tot;
    }
  }
  __syncthreads();
  {
    float* dred = (float*)(sm + DRED);
    float s = 0.f;
    #pragma unroll
    for(int ww=0; ww<8; ww++) s += dred[ww*512 + tid];
    dred[tid] = 1.f / s;                    // ivd overlays row 0
  }
  __syncthreads();

  // ================= scale V-frags by ivd[t] =================
  {
    const float* ivd = (const float*)(sm + DRED);
    #pragma unroll
    for(int it=0; it<4; it++){
      int ch = tid + it*512;
      int t0 = (ch>>7)*32 + ((ch>>6)&1)*16 + ((ch>>5)&1)*8;
      u32* pw = (u32*)(sm + VF + (size_t)ch*16);
      uint4 v = *(uint4*)pw;
      u32 wv[4] = {v.x, v.y, v.z, v.w};
      u32 nw[4];
      #pragma unroll
      for(int rr2=0;rr2<4;rr2++){
        float lo = lo16f(wv[rr2]) * ivd[t0 + 2*rr2];
        float hi = hi16f(wv[rr2]) * ivd[t0 + 2*rr2 + 1];
        nw[rr2] = cvtpk(lo, hi);
      }
      *(uint4*)pw = make_uint4(nw[0],nw[1],nw[2],nw[3]);
    }
  }
  __syncthreads();

  // ================= phase 2: both sb chains interleaved =================
  {
    f32x16 O0 = zero16(), O1 = zero16();
    #pragma unroll 2
    for(int tt=0; tt<16; tt++){
      bf16x8 Kt0 = *(const bf16x8*)(sm + KF + ((size_t)(tt*2+0)*64 + lane)*16);
      bf16x8 Kt1 = *(const bf16x8*)(sm + KF + ((size_t)(tt*2+1)*64 + lane)*16);
      bf16x8 Vt0 = *(const bf16x8*)(sm + VF + ((size_t)(tt*2+0)*64 + lane)*16);
      bf16x8 Vt1 = *(const bf16x8*)(sm + VF + ((size_t)(tt*2+1)*64 + lane)*16);
      f32x16 Da = zero16(), Db = zero16();
      Da = MFMA32(Kt0, Qfr[0][0], Da);     // D[t][s] over c (pre-scaled)
      Db = MFMA32(Kt0, Qfr[1][0], Db);
      Da = MFMA32(Kt1, Qfr[0][1], Da);
      Db = MFMA32(Kt1, Qfr[1][1], Db);
      u32 Wa[8], Wb[8];
      #pragma unroll
      for(int p=0;p<4;p++)
        #pragma unroll
        for(int hh=0;hh<2;hh++){
          Wa[p*2+hh] = cvtpk(exp2f(Da[4*p+2*hh]), exp2f(Da[4*p+2*hh+1]));
          Wb[p*2+hh] = cvtpk(exp2f(Db[4*p+2*hh]), exp2f(Db[4*p+2*hh+1]));
        }
      union { u32 wu[4]; bf16x8 v; } pa0, pa1, pb0, pb1;
      #pragma unroll
      for(int hh=0;hh<2;hh++){
        v2i ra0 = pl32swap(Wa[0+hh], Wa[2+hh]);
        pa0.wu[hh] = (u32)ra0[0]; pa0.wu[2+hh] = (u32)ra0[1];
        v2i ra1 = pl32swap(Wa[4+hh], Wa[6+hh]);
        pa1.wu[hh] = (u32)ra1[0]; pa1.wu[2+hh] = (u32)ra1[1];
        v2i rb0 = pl32swap(Wb[0+hh], Wb[2+hh]);
        pb0.wu[hh] = (u32)rb0[0]; pb0.wu[2+hh] = (u32)rb0[1];
        v2i rb1 = pl32swap(Wb[4+hh], Wb[6+hh]);
        pb1.wu[hh] = (u32)rb1[0]; pb1.wu[2+hh] = (u32)rb1[1];
      }
      O0 = MFMA32(Vt0, pa0.v, O0);
      O1 = MFMA32(Vt0, pb0.v, O1);
      O0 = MFMA32(Vt1, pa1.v, O0);
      O1 = MFMA32(Vt1, pb1.v, O1);
    }
    // epilogue: read gate from obuf, multiply, overwrite (both sb)
    #pragma unroll
    for(int sb=0; sb<2; sb++){
      const f32x16& O = sb ? O1 : O0;
      const int stg = 2*w + sb;
      const int srow = n0 + stg*32 + j;
      u32* ob32 = (u32*)(obuf + (size_t)srow*CM + head*32);
      #pragma unroll
      for(int p=0;p<4;p++)
        #pragma unroll
        for(int hh=0;hh<2;hh++){
          u32 gv = ob32[4*p + 2*gg + hh];
          float o0 = O[4*p+2*hh]   * lo16f(gv);
          float o1 = O[4*p+2*hh+1] * hi16f(gv);
          ob32[4*p + 2*gg + hh] = cvtpk(o0, o1);
        }
    }
  }
}

// --------------------------------------------------------------- outproj2 ----
// MFMA32, frag-ordered weights. 256 thr / 4 waves; wave w -> rows row0..row0+31.
__global__ __launch_bounds__(256,4) void outproj2(const u16* __restrict__ obuf,
      const u16* __restrict__ oWfh, const u16* __restrict__ oWfl,
      const float* __restrict__ ob, float* __restrict__ out){
  const int tid = threadIdx.x, w = tid>>6, lane = tid&63;
  const int gg = lane>>5, j = lane&31;
  const int row0 = blockIdx.x*128 + w*32;
  const u16* arow = obuf + (size_t)(row0 + j)*CM + gg*8;
  #pragma unroll 2
  for(int ct=0; ct<8; ct++){
    f32x16 acc = zero16();
    const u16* bh = oWfh + ((size_t)(ct*16)*64 + lane)*8;
    const u16* bl = oWfl + ((size_t)(ct*16)*64 + lane)*8;
    #pragma unroll
    for(int kc=0; kc<16; kc++){
      bf16x8 a = *(const bf16x8*)(arow + kc*16);
      acc = MFMA32(a, *(const bf16x8*)(bh + (size_t)kc*512), acc);
      acc = MFMA32(a, *(const bf16x8*)(bl + (size_t)kc*512), acc);
    }
    float bias = ob[ct*32 + j];
    #pragma unroll
    for(int reg=0; reg<16; reg++){
      int n = row0 + (reg&3) + 8*(reg>>2) + 4*gg;
      out[((size_t)(n & 511)*R_DIM + (n >> 9))*CM + ct*32 + j] = acc[reg] + bias;
    }
  }
}

// ------------------------------------------------------------------ host ----
extern "C" void kernel_launch(void* const* d_in, const int* in_sizes, int n_in,
                              void* d_out, int out_size, void* d_ws, size_t ws_size,
                              hipStream_t stream){
  const float* msa = (const float*)d_in[0];
  const float* lnw = (const float*)d_in[1];
  const float* lnb = (const float*)d_in[2];
  const float* Wq  = (const float*)d_in[3];
  const float* Wk  = (const float*)d_in[4];
  const float* Wv  = (const float*)d_in[5];
  const float* Wg  = (const float*)d_in[6];
  const float* oW  = (const float*)d_in[7];
  const float* ob  = (const float*)d_in[8];
  float* out = (float*)d_out;

  char* ws = (char*)d_ws;
  u16*   Wfrag  = (u16*)(ws);
  float* ball   = (float*)(ws + 524288);
  u16*   oWfh   = (u16*)(ws + 528384);
  u16*   oWfl   = (u16*)(ws + 659456);
  u16*   xhat   = (u16*)(ws + 790528);
  u16*   obuf   = (u16*)(ws + 101453824);

  (void)hipFuncSetAttribute((const void*)attn_fused4,
                      hipFuncAttributeMaxDynamicSharedMemorySize, ATTN_LDS);

  prep_w<<<dim3(1280), dim3(64), 0, stream>>>(lnw, lnb, Wq, Wk, Wv, Wg, oW,
                                              ball, Wfrag, oWfh, oWfl);
  ln_xhat<<<dim3(NROWS/64), dim3(256), 0, stream>>>(msa, xhat);
  attn_fused4<<<dim3(R_DIM*NH), dim3(512), ATTN_LDS, stream>>>(xhat, Wfrag, ball, obuf);
  outproj2<<<dim3(NROWS/128), dim3(256), 0, stream>>>(obuf, oWfh, oWfl, ob, out);
}

// Round 17
// 987.845 us; speedup vs baseline: 2.1906x; 1.0541x over previous
//
#include <hip/hip_runtime.h>
#include <hip/hip_bf16.h>

// MSAColumnAttention — R17: R12 exact revert (best verified: 1013us total,
// attn 705us) + gate-in-registers. R12's gate round-tripped through obuf but
// writer thread == reader thread at identical addresses -> keep the 16 cvtpk'd
// gate words in greg[2][8] (static indexing). Bit-identical output; removes
// 8 stores + 8 dependent loads per thread. R15/R16 regressions reverted.
//
// 32x32x16 bf16 MFMA layouts (R4/R6-verified):
//   A[m][k]: lane(gg,j)=gg*32+j holds row m=j, k=8gg+e ; B likewise (col n=j)
//   D[m][n]: lane(gg,j) holds col n=j, rows m=(reg&3)+8*(reg>>2)+4*gg
// Fragment construction: 8x cvt_pk + 4x permlane32_swap per D-tile (verified).
//
// ws layout (total 202,117,120 B):
//   Wfrag [8][4][16 kc][64 lane][8 bf16] @0 (512 KB) | ball [1024] f32 @524288
//   oWfh [8 mtile][16 kc][64 lane][8] bf16 @528384 | oWfl @659456
//   xhat [196608][256] bf16 @790528 | obuf [196608][256] bf16 @101453824

#define S_DIM 512
#define R_DIM 384
#define CM    256
#define NH    8
#define NROWS (S_DIM*R_DIM)

typedef unsigned short u16;
typedef unsigned int   u32;
typedef short bf16x8 __attribute__((ext_vector_type(8)));
typedef float f32x4  __attribute__((ext_vector_type(4)));
typedef float f32x16 __attribute__((ext_vector_type(16)));
typedef int   v2i    __attribute__((ext_vector_type(2)));

#define MFMA32(a,b,c) __builtin_amdgcn_mfma_f32_32x32x16_bf16((a),(b),(c),0,0,0)

__device__ __forceinline__ float lo16f(u32 u){ return __uint_as_float(u << 16); }
__device__ __forceinline__ float hi16f(u32 u){ return __uint_as_float(u & 0xffff0000u); }
__device__ __forceinline__ float b2f(u16 x){ return __uint_as_float(((u32)x) << 16); }
__device__ __forceinline__ u16 f2bf(float f){
  u32 u = __float_as_uint(f);
  return (u16)((u + 0x7fffu + ((u >> 16) & 1u)) >> 16);   // RNE
}
__device__ __forceinline__ u32 pk2(float a, float b){
  return (u32)f2bf(a) | ((u32)f2bf(b) << 16);
}
__device__ __forceinline__ u32 cvtpk(float a, float b){
  u32 d;
  asm("v_cvt_pk_bf16_f32 %0, %1, %2" : "=v"(d) : "v"(a), "v"(b));
  return d;
}
__device__ __forceinline__ v2i pl32swap(u32 a, u32 b){
  return __builtin_amdgcn_permlane32_swap((int)a, (int)b, false, false);
}
__device__ __forceinline__ f32x16 zero16(){
  f32x16 z;
  #pragma unroll
  for(int q=0;q<16;q++) z[q]=0.f;
  return z;
}

#define SC2 0.2550348653f   // (1/sqrt(32)) * log2(e), folded into K at prep (R9-proven)

// ---------------------------------------------------------------- prep_w ----
// blocks 0..1023 (h*128 + mat*32 + c): fold ln (and SC2 for K) into W row,
// write FRAG-ORDERED Wfrag[h][mat][kc][lane=gg*32+c][8] bf16; ball likewise.
// blocks 1024..1279: oW hi/lo split, FRAG-ORDERED oWfh/oWfl[mtile][kc][lane][8].
__global__ void prep_w(const float* __restrict__ lnw, const float* __restrict__ lnb,
                       const float* __restrict__ Wq, const float* __restrict__ Wk,
                       const float* __restrict__ Wv, const float* __restrict__ Wg,
                       const float* __restrict__ oW,
                       float* __restrict__ ball, u16* __restrict__ Wfrag,
                       u16* __restrict__ oWfh, u16* __restrict__ oWfl){
  int blk = blockIdx.x, t = threadIdx.x;
  // elements k(d) = 4t..4t+3 -> kc = t>>2, gg = (t>>1)&1, e0 = (t&1)*4
  int kc = t >> 2, gg = (t >> 1) & 1, e0 = (t & 1) * 4;
  if (blk < 1024){
    int h = blk >> 7, row = blk & 127, mat = row >> 5, c = row & 31;
    const float* Ws = (mat==0?Wq: mat==1?Wk: mat==2?Wv:Wg) + (size_t)(h*32+c)*CM;
    const float qs = (mat==1) ? SC2 : 1.f;   // fold softmax scale into K (f32, pre-round)
    float4 w4 = ((const float4*)Ws)[t];
    float4 l4 = ((const float4*)(lnw + (size_t)h*CM))[t];
    float4 b4 = ((const float4*)(lnb + (size_t)h*CM))[t];
    u16* dst = Wfrag + ((size_t)(((blk>>5)*16 + kc))*64 + gg*32 + c)*8 + e0;  // blk>>5 = h*4+mat
    *(uint2*)dst = make_uint2(pk2(qs*w4.x*l4.x, qs*w4.y*l4.y),
                              pk2(qs*w4.z*l4.z, qs*w4.w*l4.w));
    float p = w4.x*b4.x + w4.y*b4.y + w4.z*b4.z + w4.w*b4.w;
    #pragma unroll
    for(int off=32; off; off>>=1) p += __shfl_down(p, off);
    if(t==0) ball[blk] = qs*p;
  } else {
    int m = blk - 1024;
    float4 w4 = ((const float4*)(oW + (size_t)m*CM))[t];
    u16 h0=f2bf(w4.x), h1=f2bf(w4.y), h2=f2bf(w4.z), h3=f2bf(w4.w);
    u16 l0=f2bf(w4.x-b2f(h0)), l1=f2bf(w4.y-b2f(h1));
    u16 l2=f2bf(w4.z-b2f(h2)), l3=f2bf(w4.w-b2f(h3));
    size_t idx = ((size_t)(((m>>5)*16 + kc))*64 + gg*32 + (m&31))*8 + e0;
    *(uint2*)(oWfh + idx) = make_uint2((u32)h0|((u32)h1<<16), (u32)h2|((u32)h3<<16));
    *(uint2*)(oWfl + idx) = make_uint2((u32)l0|((u32)l1<<16), (u32)l2|((u32)l3<<16));
  }
}

// ---------------------------------------------------------------- ln_xhat ----
__global__ __launch_bounds__(256) void ln_xhat(const float* __restrict__ msa,
                                               u16* __restrict__ xhat){
  const int tid = threadIdx.x;
  const int n0 = blockIdx.x*64;
  const int i = tid >> 2, p = tid & 3;
  const int n = n0 + i, rr = n >> 9, s = n & 511;
  const float* src = msa + ((size_t)s*R_DIM + rr)*CM + p*64;
  float x[64]; float sum=0.f, sq=0.f;
  #pragma unroll
  for(int j=0;j<64;j+=4){
    float4 v = *(const float4*)(src + j);
    x[j]=v.x; x[j+1]=v.y; x[j+2]=v.z; x[j+3]=v.w;
    sum += v.x+v.y+v.z+v.w;
    sq  += v.x*v.x + v.y*v.y + v.z*v.z + v.w*v.w;
  }
  sum += __shfl_xor(sum,1); sum += __shfl_xor(sum,2);
  sq  += __shfl_xor(sq,1);  sq  += __shfl_xor(sq,2);
  float mu = sum*(1.f/256.f);
  float rs = rsqrtf(sq*(1.f/256.f) - mu*mu + 1e-5f);
  u16* dst = xhat + (size_t)n*CM + p*64;
  #pragma unroll
  for(int j=0;j<64;j+=2)
    *(u32*)(dst + j) = pk2((x[j]-mu)*rs, (x[j+1]-mu)*rs);
}

// --------------------------------------------------------------- attn_fused4 ----
// 512 thr / 8 waves, 1 block/CU (LDS-capped). Wave w owns s-tiles {2w, 2w+1}.
// proj: Wf from Wfrag (L2-hot); Q->regs, K/V->LDS, G->REGS (greg[2][8]).
// phase1: per-wave partial d -> dred; reduce -> ivd. V-scale by ivd;
// phase2: QK+exp+PV per own s-tile; epilogue gates from regs, pure store.
#define KF    0
#define VF    32768
#define DRED  65536
#define ATTN_LDS 81920

__global__ __launch_bounds__(512,1) void attn_fused4(const u16* __restrict__ xhat,
      const u16* __restrict__ Wfrag, const float* __restrict__ ball,
      u16* __restrict__ obuf){
  extern __shared__ char sm[];
  const int bid = blockIdx.x;
  const int xcd = bid & 7, kk2 = bid >> 3;
  const int r = xcd*48 + (kk2 >> 3);     // 8 heads of one r consecutive on one XCD
  const int head = kk2 & 7;
  const int tid  = threadIdx.x;
  const int w    = tid >> 6;
  const int lane = tid & 63;
  const int gg = lane >> 5, j = lane & 31;
  const int n0 = r * 512;

  bf16x8 Qfr[2][2];   // own s-tiles' Q fragments (static indexing only)
  u32 greg[2][8];     // own s-tiles' gate words (bf16x2 each; static indexing only)

  // ================= proj =================
  {
    #pragma unroll
    for(int mat=0; mat<4; mat++){
      bf16x8 Wf[16];
      const u16* wsrc = Wfrag + ((size_t)((head*4+mat)*16)*64 + lane)*8;
      #pragma unroll
      for(int kc=0;kc<16;kc++) Wf[kc] = *(const bf16x8*)(wsrc + (size_t)kc*512);
      float bias16[16]; float biasv = 0.f;
      if (mat == 2) biasv = ball[head*128 + 64 + j];
      else {
        #pragma unroll
        for(int reg=0;reg<16;reg++)
          bias16[reg] = ball[head*128 + mat*32 + (reg&3) + 8*(reg>>2) + 4*gg];
      }
      #pragma unroll
      for(int st=0; st<2; st++){
        const int stg = 2*w + st;
        const u16* xr = xhat + ((size_t)(n0 + stg*32 + j))*CM + gg*8;
        f32x16 D = zero16();
        if (mat == 2){
          #pragma unroll
          for(int kc=0;kc<16;kc++) D = MFMA32(*(const bf16x8*)(xr + kc*16), Wf[kc], D);
        } else {
          #pragma unroll
          for(int kc=0;kc<16;kc++) D = MFMA32(Wf[kc], *(const bf16x8*)(xr + kc*16), D);
        }
        if (mat == 3){                     // G: sigmoid -> registers (no obuf trip)
          #pragma unroll
          for(int p=0;p<4;p++)
            #pragma unroll
            for(int hh=0;hh<2;hh++){
              float a = D[4*p+2*hh]   + bias16[4*p+2*hh];
              float b = D[4*p+2*hh+1] + bias16[4*p+2*hh+1];
              greg[st][p*2+hh] = cvtpk(1.f/(1.f + __expf(-a)), 1.f/(1.f + __expf(-b)));
            }
        } else {
          if (mat == 2){
            #pragma unroll
            for(int q=0;q<16;q++) D[q] += biasv;
          } else {
            #pragma unroll
            for(int q=0;q<16;q++) D[q] += bias16[q];
          }
          u32 Wd[8];
          #pragma unroll
          for(int p=0;p<4;p++)
            #pragma unroll
            for(int hh=0;hh<2;hh++)
              Wd[p*2+hh] = cvtpk(D[4*p+2*hh], D[4*p+2*hh+1]);
          u32 frag[2][4];
          #pragma unroll
          for(int T=0;T<2;T++)
            #pragma unroll
            for(int hh=0;hh<2;hh++){
              v2i res = pl32swap(Wd[4*T+hh], Wd[4*T+2+hh]);
              frag[T][hh] = (u32)res[0]; frag[T][2+hh] = (u32)res[1];
            }
          if (mat == 0){
            #pragma unroll
            for(int T=0;T<2;T++){
              union { u32 wu[4]; bf16x8 v; } u;
              u.wu[0]=frag[T][0]; u.wu[1]=frag[T][1]; u.wu[2]=frag[T][2]; u.wu[3]=frag[T][3];
              Qfr[st][T] = u.v;
            }
          } else {
            char* outbase = sm + (mat==1? KF : VF);
            #pragma unroll
            for(int T=0;T<2;T++)
              *(uint4*)(outbase + ((size_t)(stg*2+T)*64 + lane)*16) =
                  make_uint4(frag[T][0],frag[T][1],frag[T][2],frag[T][3]);
          }
        }
      }
    }
  }
  __syncthreads();

  // ================= phase 1: per-wave partial d; reduce -> ivd =========
  {
    float* dred = (float*)(sm + DRED);
    #pragma unroll 2
    for(int tt=0; tt<16; tt++){
      bf16x8 Kt0 = *(const bf16x8*)(sm + KF + ((size_t)(tt*2+0)*64 + lane)*16);
      bf16x8 Kt1 = *(const bf16x8*)(sm + KF + ((size_t)(tt*2+1)*64 + lane)*16);
      float dp = 0.f;
      #pragma unroll
      for(int sb=0; sb<2; sb++){
        f32x16 D1 = zero16();
        D1 = MFMA32(Qfr[sb][0], Kt0, D1);   // D1[s][t] over c (K pre-scaled by SC2)
        D1 = MFMA32(Qfr[sb][1], Kt1, D1);
        #pragma unroll
        for(int q=0;q<16;q++) dp += exp2f(D1[q]);
      }
      v2i rr = pl32swap(__float_as_uint(dp), __float_as_uint(dp));
      float tot = __uint_as_float((u32)rr[0]) + __uint_as_float((u32)rr[1]);
      if (lane < 32) dred[w*512 + tt*32 + j] = tot;
    }
  }
  __syncthreads();
  {
    float* dred = (float*)(sm + DRED);
    float s = 0.f;
    #pragma unroll
    for(int ww=0; ww<8; ww++) s += dred[ww*512 + tid];
    dred[tid] = 1.f / s;                    // ivd overlays row 0
  }
  __syncthreads();

  // ================= scale V-frags by ivd[t] =================
  {
    const float* ivd = (const float*)(sm + DRED);
    #pragma unroll
    for(int it=0; it<4; it++){
      int ch = tid + it*512;
      int t0 = (ch>>7)*32 + ((ch>>6)&1)*16 + ((ch>>5)&1)*8;
      u32* pw = (u32*)(sm + VF + (size_t)ch*16);
      uint4 v = *(uint4*)pw;
      u32 wv[4] = {v.x, v.y, v.z, v.w};
      u32 nw[4];
      #pragma unroll
      for(int rr2=0;rr2<4;rr2++){
        float lo = lo16f(wv[rr2]) * ivd[t0 + 2*rr2];
        float hi = hi16f(wv[rr2]) * ivd[t0 + 2*rr2 + 1];
        nw[rr2] = cvtpk(lo, hi);
      }
      *(uint4*)pw = make_uint4(nw[0],nw[1],nw[2],nw[3]);
    }
  }
  __syncthreads();

  // ================= phase 2 + gated epilogue =================
  #pragma unroll
  for(int sb=0; sb<2; sb++){
    f32x16 O = zero16();
    #pragma unroll 2
    for(int tt=0; tt<16; tt++){
      bf16x8 Kt0 = *(const bf16x8*)(sm + KF + ((size_t)(tt*2+0)*64 + lane)*16);
      bf16x8 Kt1 = *(const bf16x8*)(sm + KF + ((size_t)(tt*2+1)*64 + lane)*16);
      bf16x8 Vt0 = *(const bf16x8*)(sm + VF + ((size_t)(tt*2+0)*64 + lane)*16);
      bf16x8 Vt1 = *(const bf16x8*)(sm + VF + ((size_t)(tt*2+1)*64 + lane)*16);
      f32x16 D = zero16();
      D = MFMA32(Kt0, Qfr[sb][0], D);      // D[t][s] over c (pre-scaled)
      D = MFMA32(Kt1, Qfr[sb][1], D);
      u32 Wd[8];
      #pragma unroll
      for(int p=0;p<4;p++)
        #pragma unroll
        for(int hh=0;hh<2;hh++)
          Wd[p*2+hh] = cvtpk(exp2f(D[4*p+2*hh]), exp2f(D[4*p+2*hh+1]));
      union { u32 wu[4]; bf16x8 v; } pf0, pf1;
      #pragma unroll
      for(int hh=0;hh<2;hh++){
        v2i res = pl32swap(Wd[0+hh], Wd[2+hh]);
        pf0.wu[hh] = (u32)res[0]; pf0.wu[2+hh] = (u32)res[1];
        v2i res2 = pl32swap(Wd[4+hh], Wd[6+hh]);
        pf1.wu[hh] = (u32)res2[0]; pf1.wu[2+hh] = (u32)res2[1];
      }
      O = MFMA32(Vt0, pf0.v, O);
      O = MFMA32(Vt1, pf1.v, O);
    }
    // epilogue: gate from registers, pure coalesced store to obuf
    const int stg = 2*w + sb;
    const int srow = n0 + stg*32 + j;
    u32* ob32 = (u32*)(obuf + (size_t)srow*CM + head*32);
    #pragma unroll
    for(int p=0;p<4;p++)
      #pragma unroll
      for(int hh=0;hh<2;hh++){
        u32 gv = greg[sb][p*2+hh];
        float o0 = O[4*p+2*hh]   * lo16f(gv);
        float o1 = O[4*p+2*hh+1] * hi16f(gv);
        ob32[4*p + 2*gg + hh] = cvtpk(o0, o1);
      }
  }
}

// --------------------------------------------------------------- outproj2 ----
// MFMA32, frag-ordered weights. 256 thr / 4 waves; wave w -> rows row0..row0+31.
__global__ __launch_bounds__(256,4) void outproj2(const u16* __restrict__ obuf,
      const u16* __restrict__ oWfh, const u16* __restrict__ oWfl,
      const float* __restrict__ ob, float* __restrict__ out){
  const int tid = threadIdx.x, w = tid>>6, lane = tid&63;
  const int gg = lane>>5, j = lane&31;
  const int row0 = blockIdx.x*128 + w*32;
  const u16* arow = obuf + (size_t)(row0 + j)*CM + gg*8;
  #pragma unroll 2
  for(int ct=0; ct<8; ct++){
    f32x16 acc = zero16();
    const u16* bh = oWfh + ((size_t)(ct*16)*64 + lane)*8;
    const u16* bl = oWfl + ((size_t)(ct*16)*64 + lane)*8;
    #pragma unroll
    for(int kc=0; kc<16; kc++){
      bf16x8 a = *(const bf16x8*)(arow + kc*16);
      acc = MFMA32(a, *(const bf16x8*)(bh + (size_t)kc*512), acc);
      acc = MFMA32(a, *(const bf16x8*)(bl + (size_t)kc*512), acc);
    }
    float bias = ob[ct*32 + j];
    #pragma unroll
    for(int reg=0; reg<16; reg++){
      int n = row0 + (reg&3) + 8*(reg>>2) + 4*gg;
      out[((size_t)(n & 511)*R_DIM + (n >> 9))*CM + ct*32 + j] = acc[reg] + bias;
    }
  }
}

// ------------------------------------------------------------------ host ----
extern "C" void kernel_launch(void* const* d_in, const int* in_sizes, int n_in,
                              void* d_out, int out_size, void* d_ws, size_t ws_size,
                              hipStream_t stream){
  const float* msa = (const float*)d_in[0];
  const float* lnw = (const float*)d_in[1];
  const float* lnb = (const float*)d_in[2];
  const float* Wq  = (const float*)d_in[3];
  const float* Wk  = (const float*)d_in[4];
  const float* Wv  = (const float*)d_in[5];
  const float* Wg  = (const float*)d_in[6];
  const float* oW  = (const float*)d_in[7];
  const float* ob  = (const float*)d_in[8];
  float* out = (float*)d_out;

  char* ws = (char*)d_ws;
  u16*   Wfrag  = (u16*)(ws);
  float* ball   = (float*)(ws + 524288);
  u16*   oWfh   = (u16*)(ws + 528384);
  u16*   oWfl   = (u16*)(ws + 659456);
  u16*   xhat   = (u16*)(ws + 790528);
  u16*   obuf   = (u16*)(ws + 101453824);

  (void)hipFuncSetAttribute((const void*)attn_fused4,
                      hipFuncAttributeMaxDynamicSharedMemorySize, ATTN_LDS);

  prep_w<<<dim3(1280), dim3(64), 0, stream>>>(lnw, lnb, Wq, Wk, Wv, Wg, oW,
                                              ball, Wfrag, oWfh, oWfl);
  ln_xhat<<<dim3(NROWS/64), dim3(256), 0, stream>>>(msa, xhat);
  attn_fused4<<<dim3(R_DIM*NH), dim3(512), ATTN_LDS, stream>>>(xhat, Wfrag, ball, obuf);
  outproj2<<<dim3(NROWS/128), dim3(256), 0, stream>>>(obuf, oWfh, oWfl, ob, out);
}

// Round 18
// 973.887 us; speedup vs baseline: 2.2220x; 1.0143x over previous
//
#include <hip/hip_runtime.h>
#include <hip/hip_bf16.h>

// MSAColumnAttention — R18: R17 frozen (best: 987.8us; attn 692us, gate-in-regs)
// + ln_xhat rewritten for coalescing & occupancy: 8 threads/row (32 floats each,
// halves VGPR) with interleaved chunk ownership (thread p owns float4-chunks
// c*8+p) -> 8 consecutive lanes cover 128B contiguous on load AND store.
// LN sums order-independent (ulp wobble only).
//
// 32x32x16 bf16 MFMA layouts (R4/R6-verified):
//   A[m][k]: lane(gg,j)=gg*32+j holds row m=j, k=8gg+e ; B likewise (col n=j)
//   D[m][n]: lane(gg,j) holds col n=j, rows m=(reg&3)+8*(reg>>2)+4*gg
// Fragment construction: 8x cvt_pk + 4x permlane32_swap per D-tile (verified).
//
// ws layout (total 202,117,120 B):
//   Wfrag [8][4][16 kc][64 lane][8 bf16] @0 (512 KB) | ball [1024] f32 @524288
//   oWfh [8 mtile][16 kc][64 lane][8] bf16 @528384 | oWfl @659456
//   xhat [196608][256] bf16 @790528 | obuf [196608][256] bf16 @101453824

#define S_DIM 512
#define R_DIM 384
#define CM    256
#define NH    8
#define NROWS (S_DIM*R_DIM)

typedef unsigned short u16;
typedef unsigned int   u32;
typedef short bf16x8 __attribute__((ext_vector_type(8)));
typedef float f32x4  __attribute__((ext_vector_type(4)));
typedef float f32x16 __attribute__((ext_vector_type(16)));
typedef int   v2i    __attribute__((ext_vector_type(2)));

#define MFMA32(a,b,c) __builtin_amdgcn_mfma_f32_32x32x16_bf16((a),(b),(c),0,0,0)

__device__ __forceinline__ float lo16f(u32 u){ return __uint_as_float(u << 16); }
__device__ __forceinline__ float hi16f(u32 u){ return __uint_as_float(u & 0xffff0000u); }
__device__ __forceinline__ float b2f(u16 x){ return __uint_as_float(((u32)x) << 16); }
__device__ __forceinline__ u16 f2bf(float f){
  u32 u = __float_as_uint(f);
  return (u16)((u + 0x7fffu + ((u >> 16) & 1u)) >> 16);   // RNE
}
__device__ __forceinline__ u32 pk2(float a, float b){
  return (u32)f2bf(a) | ((u32)f2bf(b) << 16);
}
__device__ __forceinline__ u32 cvtpk(float a, float b){
  u32 d;
  asm("v_cvt_pk_bf16_f32 %0, %1, %2" : "=v"(d) : "v"(a), "v"(b));
  return d;
}
__device__ __forceinline__ v2i pl32swap(u32 a, u32 b){
  return __builtin_amdgcn_permlane32_swap((int)a, (int)b, false, false);
}
__device__ __forceinline__ f32x16 zero16(){
  f32x16 z;
  #pragma unroll
  for(int q=0;q<16;q++) z[q]=0.f;
  return z;
}

#define SC2 0.2550348653f   // (1/sqrt(32)) * log2(e), folded into K at prep (R9-proven)

// ---------------------------------------------------------------- prep_w ----
// blocks 0..1023 (h*128 + mat*32 + c): fold ln (and SC2 for K) into W row,
// write FRAG-ORDERED Wfrag[h][mat][kc][lane=gg*32+c][8] bf16; ball likewise.
// blocks 1024..1279: oW hi/lo split, FRAG-ORDERED oWfh/oWfl[mtile][kc][lane][8].
__global__ void prep_w(const float* __restrict__ lnw, const float* __restrict__ lnb,
                       const float* __restrict__ Wq, const float* __restrict__ Wk,
                       const float* __restrict__ Wv, const float* __restrict__ Wg,
                       const float* __restrict__ oW,
                       float* __restrict__ ball, u16* __restrict__ Wfrag,
                       u16* __restrict__ oWfh, u16* __restrict__ oWfl){
  int blk = blockIdx.x, t = threadIdx.x;
  // elements k(d) = 4t..4t+3 -> kc = t>>2, gg = (t>>1)&1, e0 = (t&1)*4
  int kc = t >> 2, gg = (t >> 1) & 1, e0 = (t & 1) * 4;
  if (blk < 1024){
    int h = blk >> 7, row = blk & 127, mat = row >> 5, c = row & 31;
    const float* Ws = (mat==0?Wq: mat==1?Wk: mat==2?Wv:Wg) + (size_t)(h*32+c)*CM;
    const float qs = (mat==1) ? SC2 : 1.f;   // fold softmax scale into K (f32, pre-round)
    float4 w4 = ((const float4*)Ws)[t];
    float4 l4 = ((const float4*)(lnw + (size_t)h*CM))[t];
    float4 b4 = ((const float4*)(lnb + (size_t)h*CM))[t];
    u16* dst = Wfrag + ((size_t)(((blk>>5)*16 + kc))*64 + gg*32 + c)*8 + e0;  // blk>>5 = h*4+mat
    *(uint2*)dst = make_uint2(pk2(qs*w4.x*l4.x, qs*w4.y*l4.y),
                              pk2(qs*w4.z*l4.z, qs*w4.w*l4.w));
    float p = w4.x*b4.x + w4.y*b4.y + w4.z*b4.z + w4.w*b4.w;
    #pragma unroll
    for(int off=32; off; off>>=1) p += __shfl_down(p, off);
    if(t==0) ball[blk] = qs*p;
  } else {
    int m = blk - 1024;
    float4 w4 = ((const float4*)(oW + (size_t)m*CM))[t];
    u16 h0=f2bf(w4.x), h1=f2bf(w4.y), h2=f2bf(w4.z), h3=f2bf(w4.w);
    u16 l0=f2bf(w4.x-b2f(h0)), l1=f2bf(w4.y-b2f(h1));
    u16 l2=f2bf(w4.z-b2f(h2)), l3=f2bf(w4.w-b2f(h3));
    size_t idx = ((size_t)(((m>>5)*16 + kc))*64 + gg*32 + (m&31))*8 + e0;
    *(uint2*)(oWfh + idx) = make_uint2((u32)h0|((u32)h1<<16), (u32)h2|((u32)h3<<16));
    *(uint2*)(oWfl + idx) = make_uint2((u32)l0|((u32)l1<<16), (u32)l2|((u32)l3<<16));
  }
}

// ---------------------------------------------------------------- ln_xhat ----
// 8 threads/row, 32 floats each, interleaved float4-chunk ownership (ch = c*8+p):
// 8 consecutive lanes -> 128B contiguous on load and store. Stats via 3 xor-shfls.
__global__ __launch_bounds__(256) void ln_xhat(const float* __restrict__ msa,
                                               u16* __restrict__ xhat){
  const int tid = threadIdx.x;
  const int n0 = blockIdx.x*32;
  const int i = tid >> 3, p = tid & 7;
  const int n = n0 + i, rr = n >> 9, s = n & 511;
  const float* src = msa + ((size_t)s*R_DIM + rr)*CM;
  float x[32]; float sum=0.f, sq=0.f;
  #pragma unroll
  for(int c=0;c<8;c++){
    float4 v = ((const float4*)src)[c*8 + p];
    x[c*4]=v.x; x[c*4+1]=v.y; x[c*4+2]=v.z; x[c*4+3]=v.w;
    sum += v.x+v.y+v.z+v.w;
    sq  += v.x*v.x + v.y*v.y + v.z*v.z + v.w*v.w;
  }
  sum += __shfl_xor(sum,1); sum += __shfl_xor(sum,2); sum += __shfl_xor(sum,4);
  sq  += __shfl_xor(sq,1);  sq  += __shfl_xor(sq,2);  sq  += __shfl_xor(sq,4);
  float mu = sum*(1.f/256.f);
  float rs = rsqrtf(sq*(1.f/256.f) - mu*mu + 1e-5f);
  uint2* dst = (uint2*)(xhat + (size_t)n*CM);
  #pragma unroll
  for(int c=0;c<8;c++)
    dst[c*8 + p] = make_uint2(pk2((x[c*4]-mu)*rs,   (x[c*4+1]-mu)*rs),
                              pk2((x[c*4+2]-mu)*rs, (x[c*4+3]-mu)*rs));
}

// --------------------------------------------------------------- attn_fused4 ----
// R17 FROZEN: 512 thr / 8 waves, 1 block/CU (LDS-capped). Wave w owns s-tiles
// {2w, 2w+1}. proj: Wf from Wfrag (L2-hot); Q->regs, K/V->LDS, G->REGS.
// phase1: per-wave partial d -> dred; reduce -> ivd. V-scale by ivd;
// phase2: QK+exp+PV per own s-tile; epilogue gates from regs, pure store.
#define KF    0
#define VF    32768
#define DRED  65536
#define ATTN_LDS 81920

__global__ __launch_bounds__(512,1) void attn_fused4(const u16* __restrict__ xhat,
      const u16* __restrict__ Wfrag, const float* __restrict__ ball,
      u16* __restrict__ obuf){
  extern __shared__ char sm[];
  const int bid = blockIdx.x;
  const int xcd = bid & 7, kk2 = bid >> 3;
  const int r = xcd*48 + (kk2 >> 3);     // 8 heads of one r consecutive on one XCD
  const int head = kk2 & 7;
  const int tid  = threadIdx.x;
  const int w    = tid >> 6;
  const int lane = tid & 63;
  const int gg = lane >> 5, j = lane & 31;
  const int n0 = r * 512;

  bf16x8 Qfr[2][2];   // own s-tiles' Q fragments (static indexing only)
  u32 greg[2][8];     // own s-tiles' gate words (bf16x2 each; static indexing only)

  // ================= proj =================
  {
    #pragma unroll
    for(int mat=0; mat<4; mat++){
      bf16x8 Wf[16];
      const u16* wsrc = Wfrag + ((size_t)((head*4+mat)*16)*64 + lane)*8;
      #pragma unroll
      for(int kc=0;kc<16;kc++) Wf[kc] = *(const bf16x8*)(wsrc + (size_t)kc*512);
      float bias16[16]; float biasv = 0.f;
      if (mat == 2) biasv = ball[head*128 + 64 + j];
      else {
        #pragma unroll
        for(int reg=0;reg<16;reg++)
          bias16[reg] = ball[head*128 + mat*32 + (reg&3) + 8*(reg>>2) + 4*gg];
      }
      #pragma unroll
      for(int st=0; st<2; st++){
        const int stg = 2*w + st;
        const u16* xr = xhat + ((size_t)(n0 + stg*32 + j))*CM + gg*8;
        f32x16 D = zero16();
        if (mat == 2){
          #pragma unroll
          for(int kc=0;kc<16;kc++) D = MFMA32(*(const bf16x8*)(xr + kc*16), Wf[kc], D);
        } else {
          #pragma unroll
          for(int kc=0;kc<16;kc++) D = MFMA32(Wf[kc], *(const bf16x8*)(xr + kc*16), D);
        }
        if (mat == 3){                     // G: sigmoid -> registers (no obuf trip)
          #pragma unroll
          for(int p=0;p<4;p++)
            #pragma unroll
            for(int hh=0;hh<2;hh++){
              float a = D[4*p+2*hh]   + bias16[4*p+2*hh];
              float b = D[4*p+2*hh+1] + bias16[4*p+2*hh+1];
              greg[st][p*2+hh] = cvtpk(1.f/(1.f + __expf(-a)), 1.f/(1.f + __expf(-b)));
            }
        } else {
          if (mat == 2){
            #pragma unroll
            for(int q=0;q<16;q++) D[q] += biasv;
          } else {
            #pragma unroll
            for(int q=0;q<16;q++) D[q] += bias16[q];
          }
          u32 Wd[8];
          #pragma unroll
          for(int p=0;p<4;p++)
            #pragma unroll
            for(int hh=0;hh<2;hh++)
              Wd[p*2+hh] = cvtpk(D[4*p+2*hh], D[4*p+2*hh+1]);
          u32 frag[2][4];
          #pragma unroll
          for(int T=0;T<2;T++)
            #pragma unroll
            for(int hh=0;hh<2;hh++){
              v2i res = pl32swap(Wd[4*T+hh], Wd[4*T+2+hh]);
              frag[T][hh] = (u32)res[0]; frag[T][2+hh] = (u32)res[1];
            }
          if (mat == 0){
            #pragma unroll
            for(int T=0;T<2;T++){
              union { u32 wu[4]; bf16x8 v; } u;
              u.wu[0]=frag[T][0]; u.wu[1]=frag[T][1]; u.wu[2]=frag[T][2]; u.wu[3]=frag[T][3];
              Qfr[st][T] = u.v;
            }
          } else {
            char* outbase = sm + (mat==1? KF : VF);
            #pragma unroll
            for(int T=0;T<2;T++)
              *(uint4*)(outbase + ((size_t)(stg*2+T)*64 + lane)*16) =
                  make_uint4(frag[T][0],frag[T][1],frag[T][2],frag[T][3]);
          }
        }
      }
    }
  }
  __syncthreads();

  // ================= phase 1: per-wave partial d; reduce -> ivd =========
  {
    float* dred = (float*)(sm + DRED);
    #pragma unroll 2
    for(int tt=0; tt<16; tt++){
      bf16x8 Kt0 = *(const bf16x8*)(sm + KF + ((size_t)(tt*2+0)*64 + lane)*16);
      bf16x8 Kt1 = *(const bf16x8*)(sm + KF + ((size_t)(tt*2+1)*64 + lane)*16);
      float dp = 0.f;
      #pragma unroll
      for(int sb=0; sb<2; sb++){
        f32x16 D1 = zero16();
        D1 = MFMA32(Qfr[sb][0], Kt0, D1);   // D1[s][t] over c (K pre-scaled by SC2)
        D1 = MFMA32(Qfr[sb][1], Kt1, D1);
        #pragma unroll
        for(int q=0;q<16;q++) dp += exp2f(D1[q]);
      }
      v2i rr = pl32swap(__float_as_uint(dp), __float_as_uint(dp));
      float tot = __uint_as_float((u32)rr[0]) + __uint_as_float((u32)rr[1]);
      if (lane < 32) dred[w*512 + tt*32 + j] = tot;
    }
  }
  __syncthreads();
  {
    float* dred = (float*)(sm + DRED);
    float s = 0.f;
    #pragma unroll
    for(int ww=0; ww<8; ww++) s += dred[ww*512 + tid];
    dred[tid] = 1.f / s;                    // ivd overlays row 0
  }
  __syncthreads();

  // ================= scale V-frags by ivd[t] =================
  {
    const float* ivd = (const float*)(sm + DRED);
    #pragma unroll
    for(int it=0; it<4; it++){
      int ch = tid + it*512;
      int t0 = (ch>>7)*32 + ((ch>>6)&1)*16 + ((ch>>5)&1)*8;
      u32* pw = (u32*)(sm + VF + (size_t)ch*16);
      uint4 v = *(uint4*)pw;
      u32 wv[4] = {v.x, v.y, v.z, v.w};
      u32 nw[4];
      #pragma unroll
      for(int rr2=0;rr2<4;rr2++){
        float lo = lo16f(wv[rr2]) * ivd[t0 + 2*rr2];
        float hi = hi16f(wv[rr2]) * ivd[t0 + 2*rr2 + 1];
        nw[rr2] = cvtpk(lo, hi);
      }
      *(uint4*)pw = make_uint4(nw[0],nw[1],nw[2],nw[3]);
    }
  }
  __syncthreads();

  // ================= phase 2 + gated epilogue =================
  #pragma unroll
  for(int sb=0; sb<2; sb++){
    f32x16 O = zero16();
    #pragma unroll 2
    for(int tt=0; tt<16; tt++){
      bf16x8 Kt0 = *(const bf16x8*)(sm + KF + ((size_t)(tt*2+0)*64 + lane)*16);
      bf16x8 Kt1 = *(const bf16x8*)(sm + KF + ((size_t)(tt*2+1)*64 + lane)*16);
      bf16x8 Vt0 = *(const bf16x8*)(sm + VF + ((size_t)(tt*2+0)*64 + lane)*16);
      bf16x8 Vt1 = *(const bf16x8*)(sm + VF + ((size_t)(tt*2+1)*64 + lane)*16);
      f32x16 D = zero16();
      D = MFMA32(Kt0, Qfr[sb][0], D);      // D[t][s] over c (pre-scaled)
      D = MFMA32(Kt1, Qfr[sb][1], D);
      u32 Wd[8];
      #pragma unroll
      for(int p=0;p<4;p++)
        #pragma unroll
        for(int hh=0;hh<2;hh++)
          Wd[p*2+hh] = cvtpk(exp2f(D[4*p+2*hh]), exp2f(D[4*p+2*hh+1]));
      union { u32 wu[4]; bf16x8 v; } pf0, pf1;
      #pragma unroll
      for(int hh=0;hh<2;hh++){
        v2i res = pl32swap(Wd[0+hh], Wd[2+hh]);
        pf0.wu[hh] = (u32)res[0]; pf0.wu[2+hh] = (u32)res[1];
        v2i res2 = pl32swap(Wd[4+hh], Wd[6+hh]);
        pf1.wu[hh] = (u32)res2[0]; pf1.wu[2+hh] = (u32)res2[1];
      }
      O = MFMA32(Vt0, pf0.v, O);
      O = MFMA32(Vt1, pf1.v, O);
    }
    // epilogue: gate from registers, pure coalesced store to obuf
    const int stg = 2*w + sb;
    const int srow = n0 + stg*32 + j;
    u32* ob32 = (u32*)(obuf + (size_t)srow*CM + head*32);
    #pragma unroll
    for(int p=0;p<4;p++)
      #pragma unroll
      for(int hh=0;hh<2;hh++){
        u32 gv = greg[sb][p*2+hh];
        float o0 = O[4*p+2*hh]   * lo16f(gv);
        float o1 = O[4*p+2*hh+1] * hi16f(gv);
        ob32[4*p + 2*gg + hh] = cvtpk(o0, o1);
      }
  }
}

// --------------------------------------------------------------- outproj2 ----
// MFMA32, frag-ordered weights. 256 thr / 4 waves; wave w -> rows row0..row0+31.
__global__ __launch_bounds__(256,4) void outproj2(const u16* __restrict__ obuf,
      const u16* __restrict__ oWfh, const u16* __restrict__ oWfl,
      const float* __restrict__ ob, float* __restrict__ out){
  const int tid = threadIdx.x, w = tid>>6, lane = tid&63;
  const int gg = lane>>5, j = lane&31;
  const int row0 = blockIdx.x*128 + w*32;
  const u16* arow = obuf + (size_t)(row0 + j)*CM + gg*8;
  #pragma unroll 2
  for(int ct=0; ct<8; ct++){
    f32x16 acc = zero16();
    const u16* bh = oWfh + ((size_t)(ct*16)*64 + lane)*8;
    const u16* bl = oWfl + ((size_t)(ct*16)*64 + lane)*8;
    #pragma unroll
    for(int kc=0; kc<16; kc++){
      bf16x8 a = *(const bf16x8*)(arow + kc*16);
      acc = MFMA32(a, *(const bf16x8*)(bh + (size_t)kc*512), acc);
      acc = MFMA32(a, *(const bf16x8*)(bl + (size_t)kc*512), acc);
    }
    float bias = ob[ct*32 + j];
    #pragma unroll
    for(int reg=0; reg<16; reg++){
      int n = row0 + (reg&3) + 8*(reg>>2) + 4*gg;
      out[((size_t)(n & 511)*R_DIM + (n >> 9))*CM + ct*32 + j] = acc[reg] + bias;
    }
  }
}

// ------------------------------------------------------------------ host ----
extern "C" void kernel_launch(void* const* d_in, const int* in_sizes, int n_in,
                              void* d_out, int out_size, void* d_ws, size_t ws_size,
                              hipStream_t stream){
  const float* msa = (const float*)d_in[0];
  const float* lnw = (const float*)d_in[1];
  const float* lnb = (const float*)d_in[2];
  const float* Wq  = (const float*)d_in[3];
  const float* Wk  = (const float*)d_in[4];
  const float* Wv  = (const float*)d_in[5];
  const float* Wg  = (const float*)d_in[6];
  const float* oW  = (const float*)d_in[7];
  const float* ob  = (const float*)d_in[8];
  float* out = (float*)d_out;

  char* ws = (char*)d_ws;
  u16*   Wfrag  = (u16*)(ws);
  float* ball   = (float*)(ws + 524288);
  u16*   oWfh   = (u16*)(ws + 528384);
  u16*   oWfl   = (u16*)(ws + 659456);
  u16*   xhat   = (u16*)(ws + 790528);
  u16*   obuf   = (u16*)(ws + 101453824);

  (void)hipFuncSetAttribute((const void*)attn_fused4,
                      hipFuncAttributeMaxDynamicSharedMemorySize, ATTN_LDS);

  prep_w<<<dim3(1280), dim3(64), 0, stream>>>(lnw, lnb, Wq, Wk, Wv, Wg, oW,
                                              ball, Wfrag, oWfh, oWfl);
  ln_xhat<<<dim3(NROWS/32), dim3(256), 0, stream>>>(msa, xhat);
  attn_fused4<<<dim3(R_DIM*NH), dim3(512), ATTN_LDS, stream>>>(xhat, Wfrag, ball, obuf);
  outproj2<<<dim3(NROWS/128), dim3(256), 0, stream>>>(obuf, oWfh, oWfl, ob, out);
}

// Round 19
// 970.275 us; speedup vs baseline: 2.2302x; 1.0037x over previous
//
#include <hip/hip_runtime.h>
#include <hip/hip_bf16.h>

// MSAColumnAttention — R19: R18 frozen (973.9us; attn 693, gate-in-regs,
// coalesced ln_xhat) + two micro-ILP shaves in attn:
//   (1) phase-1 dp split into 4 independent accumulator chains (reassociation
//       of a positive sum; R13's failure was the raw-TRANS builtin, not this),
//   (2) epilogue stores paired into uint2 (adjacent words 4p+2gg, +1).
// Structure settled: 2 waves/SIMD reg-file cap (R9/R10/R13/R14/R16 all blocked).
//
// 32x32x16 bf16 MFMA layouts (R4/R6-verified):
//   A[m][k]: lane(gg,j)=gg*32+j holds row m=j, k=8gg+e ; B likewise (col n=j)
//   D[m][n]: lane(gg,j) holds col n=j, rows m=(reg&3)+8*(reg>>2)+4*gg
// Fragment construction: 8x cvt_pk + 4x permlane32_swap per D-tile (verified).
//
// ws layout (total 202,117,120 B):
//   Wfrag [8][4][16 kc][64 lane][8 bf16] @0 (512 KB) | ball [1024] f32 @524288
//   oWfh [8 mtile][16 kc][64 lane][8] bf16 @528384 | oWfl @659456
//   xhat [196608][256] bf16 @790528 | obuf [196608][256] bf16 @101453824

#define S_DIM 512
#define R_DIM 384
#define CM    256
#define NH    8
#define NROWS (S_DIM*R_DIM)

typedef unsigned short u16;
typedef unsigned int   u32;
typedef short bf16x8 __attribute__((ext_vector_type(8)));
typedef float f32x4  __attribute__((ext_vector_type(4)));
typedef float f32x16 __attribute__((ext_vector_type(16)));
typedef int   v2i    __attribute__((ext_vector_type(2)));

#define MFMA32(a,b,c) __builtin_amdgcn_mfma_f32_32x32x16_bf16((a),(b),(c),0,0,0)

__device__ __forceinline__ float lo16f(u32 u){ return __uint_as_float(u << 16); }
__device__ __forceinline__ float hi16f(u32 u){ return __uint_as_float(u & 0xffff0000u); }
__device__ __forceinline__ float b2f(u16 x){ return __uint_as_float(((u32)x) << 16); }
__device__ __forceinline__ u16 f2bf(float f){
  u32 u = __float_as_uint(f);
  return (u16)((u + 0x7fffu + ((u >> 16) & 1u)) >> 16);   // RNE
}
__device__ __forceinline__ u32 pk2(float a, float b){
  return (u32)f2bf(a) | ((u32)f2bf(b) << 16);
}
__device__ __forceinline__ u32 cvtpk(float a, float b){
  u32 d;
  asm("v_cvt_pk_bf16_f32 %0, %1, %2" : "=v"(d) : "v"(a), "v"(b));
  return d;
}
__device__ __forceinline__ v2i pl32swap(u32 a, u32 b){
  return __builtin_amdgcn_permlane32_swap((int)a, (int)b, false, false);
}
__device__ __forceinline__ f32x16 zero16(){
  f32x16 z;
  #pragma unroll
  for(int q=0;q<16;q++) z[q]=0.f;
  return z;
}

#define SC2 0.2550348653f   // (1/sqrt(32)) * log2(e), folded into K at prep (R9-proven)

// ---------------------------------------------------------------- prep_w ----
// blocks 0..1023 (h*128 + mat*32 + c): fold ln (and SC2 for K) into W row,
// write FRAG-ORDERED Wfrag[h][mat][kc][lane=gg*32+c][8] bf16; ball likewise.
// blocks 1024..1279: oW hi/lo split, FRAG-ORDERED oWfh/oWfl[mtile][kc][lane][8].
__global__ void prep_w(const float* __restrict__ lnw, const float* __restrict__ lnb,
                       const float* __restrict__ Wq, const float* __restrict__ Wk,
                       const float* __restrict__ Wv, const float* __restrict__ Wg,
                       const float* __restrict__ oW,
                       float* __restrict__ ball, u16* __restrict__ Wfrag,
                       u16* __restrict__ oWfh, u16* __restrict__ oWfl){
  int blk = blockIdx.x, t = threadIdx.x;
  // elements k(d) = 4t..4t+3 -> kc = t>>2, gg = (t>>1)&1, e0 = (t&1)*4
  int kc = t >> 2, gg = (t >> 1) & 1, e0 = (t & 1) * 4;
  if (blk < 1024){
    int h = blk >> 7, row = blk & 127, mat = row >> 5, c = row & 31;
    const float* Ws = (mat==0?Wq: mat==1?Wk: mat==2?Wv:Wg) + (size_t)(h*32+c)*CM;
    const float qs = (mat==1) ? SC2 : 1.f;   // fold softmax scale into K (f32, pre-round)
    float4 w4 = ((const float4*)Ws)[t];
    float4 l4 = ((const float4*)(lnw + (size_t)h*CM))[t];
    float4 b4 = ((const float4*)(lnb + (size_t)h*CM))[t];
    u16* dst = Wfrag + ((size_t)(((blk>>5)*16 + kc))*64 + gg*32 + c)*8 + e0;  // blk>>5 = h*4+mat
    *(uint2*)dst = make_uint2(pk2(qs*w4.x*l4.x, qs*w4.y*l4.y),
                              pk2(qs*w4.z*l4.z, qs*w4.w*l4.w));
    float p = w4.x*b4.x + w4.y*b4.y + w4.z*b4.z + w4.w*b4.w;
    #pragma unroll
    for(int off=32; off; off>>=1) p += __shfl_down(p, off);
    if(t==0) ball[blk] = qs*p;
  } else {
    int m = blk - 1024;
    float4 w4 = ((const float4*)(oW + (size_t)m*CM))[t];
    u16 h0=f2bf(w4.x), h1=f2bf(w4.y), h2=f2bf(w4.z), h3=f2bf(w4.w);
    u16 l0=f2bf(w4.x-b2f(h0)), l1=f2bf(w4.y-b2f(h1));
    u16 l2=f2bf(w4.z-b2f(h2)), l3=f2bf(w4.w-b2f(h3));
    size_t idx = ((size_t)(((m>>5)*16 + kc))*64 + gg*32 + (m&31))*8 + e0;
    *(uint2*)(oWfh + idx) = make_uint2((u32)h0|((u32)h1<<16), (u32)h2|((u32)h3<<16));
    *(uint2*)(oWfl + idx) = make_uint2((u32)l0|((u32)l1<<16), (u32)l2|((u32)l3<<16));
  }
}

// ---------------------------------------------------------------- ln_xhat ----
// 8 threads/row, 32 floats each, interleaved float4-chunk ownership (ch = c*8+p):
// 8 consecutive lanes -> 128B contiguous on load and store. Stats via 3 xor-shfls.
__global__ __launch_bounds__(256) void ln_xhat(const float* __restrict__ msa,
                                               u16* __restrict__ xhat){
  const int tid = threadIdx.x;
  const int n0 = blockIdx.x*32;
  const int i = tid >> 3, p = tid & 7;
  const int n = n0 + i, rr = n >> 9, s = n & 511;
  const float* src = msa + ((size_t)s*R_DIM + rr)*CM;
  float x[32]; float sum=0.f, sq=0.f;
  #pragma unroll
  for(int c=0;c<8;c++){
    float4 v = ((const float4*)src)[c*8 + p];
    x[c*4]=v.x; x[c*4+1]=v.y; x[c*4+2]=v.z; x[c*4+3]=v.w;
    sum += v.x+v.y+v.z+v.w;
    sq  += v.x*v.x + v.y*v.y + v.z*v.z + v.w*v.w;
  }
  sum += __shfl_xor(sum,1); sum += __shfl_xor(sum,2); sum += __shfl_xor(sum,4);
  sq  += __shfl_xor(sq,1);  sq  += __shfl_xor(sq,2);  sq  += __shfl_xor(sq,4);
  float mu = sum*(1.f/256.f);
  float rs = rsqrtf(sq*(1.f/256.f) - mu*mu + 1e-5f);
  uint2* dst = (uint2*)(xhat + (size_t)n*CM);
  #pragma unroll
  for(int c=0;c<8;c++)
    dst[c*8 + p] = make_uint2(pk2((x[c*4]-mu)*rs,   (x[c*4+1]-mu)*rs),
                              pk2((x[c*4+2]-mu)*rs, (x[c*4+3]-mu)*rs));
}

// --------------------------------------------------------------- attn_fused4 ----
// 512 thr / 8 waves, 1 block/CU (LDS-capped). Wave w owns s-tiles {2w, 2w+1}.
// proj: Wf from Wfrag (L2-hot); Q->regs, K/V->LDS, G->REGS.
// phase1: per-wave partial d (4-chain split) -> dred; reduce -> ivd.
// V-scale by ivd; phase2: QK+exp+PV per own s-tile; epilogue paired uint2 stores.
#define KF    0
#define VF    32768
#define DRED  65536
#define ATTN_LDS 81920

__global__ __launch_bounds__(512,1) void attn_fused4(const u16* __restrict__ xhat,
      const u16* __restrict__ Wfrag, const float* __restrict__ ball,
      u16* __restrict__ obuf){
  extern __shared__ char sm[];
  const int bid = blockIdx.x;
  const int xcd = bid & 7, kk2 = bid >> 3;
  const int r = xcd*48 + (kk2 >> 3);     // 8 heads of one r consecutive on one XCD
  const int head = kk2 & 7;
  const int tid  = threadIdx.x;
  const int w    = tid >> 6;
  const int lane = tid & 63;
  const int gg = lane >> 5, j = lane & 31;
  const int n0 = r * 512;

  bf16x8 Qfr[2][2];   // own s-tiles' Q fragments (static indexing only)
  u32 greg[2][8];     // own s-tiles' gate words (bf16x2 each; static indexing only)

  // ================= proj =================
  {
    #pragma unroll
    for(int mat=0; mat<4; mat++){
      bf16x8 Wf[16];
      const u16* wsrc = Wfrag + ((size_t)((head*4+mat)*16)*64 + lane)*8;
      #pragma unroll
      for(int kc=0;kc<16;kc++) Wf[kc] = *(const bf16x8*)(wsrc + (size_t)kc*512);
      float bias16[16]; float biasv = 0.f;
      if (mat == 2) biasv = ball[head*128 + 64 + j];
      else {
        #pragma unroll
        for(int reg=0;reg<16;reg++)
          bias16[reg] = ball[head*128 + mat*32 + (reg&3) + 8*(reg>>2) + 4*gg];
      }
      #pragma unroll
      for(int st=0; st<2; st++){
        const int stg = 2*w + st;
        const u16* xr = xhat + ((size_t)(n0 + stg*32 + j))*CM + gg*8;
        f32x16 D = zero16();
        if (mat == 2){
          #pragma unroll
          for(int kc=0;kc<16;kc++) D = MFMA32(*(const bf16x8*)(xr + kc*16), Wf[kc], D);
        } else {
          #pragma unroll
          for(int kc=0;kc<16;kc++) D = MFMA32(Wf[kc], *(const bf16x8*)(xr + kc*16), D);
        }
        if (mat == 3){                     // G: sigmoid -> registers (no obuf trip)
          #pragma unroll
          for(int p=0;p<4;p++)
            #pragma unroll
            for(int hh=0;hh<2;hh++){
              float a = D[4*p+2*hh]   + bias16[4*p+2*hh];
              float b = D[4*p+2*hh+1] + bias16[4*p+2*hh+1];
              greg[st][p*2+hh] = cvtpk(1.f/(1.f + __expf(-a)), 1.f/(1.f + __expf(-b)));
            }
        } else {
          if (mat == 2){
            #pragma unroll
            for(int q=0;q<16;q++) D[q] += biasv;
          } else {
            #pragma unroll
            for(int q=0;q<16;q++) D[q] += bias16[q];
          }
          u32 Wd[8];
          #pragma unroll
          for(int p=0;p<4;p++)
            #pragma unroll
            for(int hh=0;hh<2;hh++)
              Wd[p*2+hh] = cvtpk(D[4*p+2*hh], D[4*p+2*hh+1]);
          u32 frag[2][4];
          #pragma unroll
          for(int T=0;T<2;T++)
            #pragma unroll
            for(int hh=0;hh<2;hh++){
              v2i res = pl32swap(Wd[4*T+hh], Wd[4*T+2+hh]);
              frag[T][hh] = (u32)res[0]; frag[T][2+hh] = (u32)res[1];
            }
          if (mat == 0){
            #pragma unroll
            for(int T=0;T<2;T++){
              union { u32 wu[4]; bf16x8 v; } u;
              u.wu[0]=frag[T][0]; u.wu[1]=frag[T][1]; u.wu[2]=frag[T][2]; u.wu[3]=frag[T][3];
              Qfr[st][T] = u.v;
            }
          } else {
            char* outbase = sm + (mat==1? KF : VF);
            #pragma unroll
            for(int T=0;T<2;T++)
              *(uint4*)(outbase + ((size_t)(stg*2+T)*64 + lane)*16) =
                  make_uint4(frag[T][0],frag[T][1],frag[T][2],frag[T][3]);
          }
        }
      }
    }
  }
  __syncthreads();

  // ================= phase 1: per-wave partial d (4 chains); reduce -> ivd ====
  {
    float* dred = (float*)(sm + DRED);
    #pragma unroll 2
    for(int tt=0; tt<16; tt++){
      bf16x8 Kt0 = *(const bf16x8*)(sm + KF + ((size_t)(tt*2+0)*64 + lane)*16);
      bf16x8 Kt1 = *(const bf16x8*)(sm + KF + ((size_t)(tt*2+1)*64 + lane)*16);
      float d0=0.f, d1=0.f, d2=0.f, d3=0.f;
      #pragma unroll
      for(int sb=0; sb<2; sb++){
        f32x16 D1 = zero16();
        D1 = MFMA32(Qfr[sb][0], Kt0, D1);   // D1[s][t] over c (K pre-scaled by SC2)
        D1 = MFMA32(Qfr[sb][1], Kt1, D1);
        #pragma unroll
        for(int q=0;q<16;q+=4){
          d0 += exp2f(D1[q]);   d1 += exp2f(D1[q+1]);
          d2 += exp2f(D1[q+2]); d3 += exp2f(D1[q+3]);
        }
      }
      float dp = (d0+d1)+(d2+d3);
      v2i rr = pl32swap(__float_as_uint(dp), __float_as_uint(dp));
      float tot = __uint_as_float((u32)rr[0]) + __uint_as_float((u32)rr[1]);
      if (lane < 32) dred[w*512 + tt*32 + j] = tot;
    }
  }
  __syncthreads();
  {
    float* dred = (float*)(sm + DRED);
    float s = 0.f;
    #pragma unroll
    for(int ww=0; ww<8; ww++) s += dred[ww*512 + tid];
    dred[tid] = 1.f / s;                    // ivd overlays row 0
  }
  __syncthreads();

  // ================= scale V-frags by ivd[t] =================
  {
    const float* ivd = (const float*)(sm + DRED);
    #pragma unroll
    for(int it=0; it<4; it++){
      int ch = tid + it*512;
      int t0 = (ch>>7)*32 + ((ch>>6)&1)*16 + ((ch>>5)&1)*8;
      u32* pw = (u32*)(sm + VF + (size_t)ch*16);
      uint4 v = *(uint4*)pw;
      u32 wv[4] = {v.x, v.y, v.z, v.w};
      u32 nw[4];
      #pragma unroll
      for(int rr2=0;rr2<4;rr2++){
        float lo = lo16f(wv[rr2]) * ivd[t0 + 2*rr2];
        float hi = hi16f(wv[rr2]) * ivd[t0 + 2*rr2 + 1];
        nw[rr2] = cvtpk(lo, hi);
      }
      *(uint4*)pw = make_uint4(nw[0],nw[1],nw[2],nw[3]);
    }
  }
  __syncthreads();

  // ================= phase 2 + gated epilogue =================
  #pragma unroll
  for(int sb=0; sb<2; sb++){
    f32x16 O = zero16();
    #pragma unroll 2
    for(int tt=0; tt<16; tt++){
      bf16x8 Kt0 = *(const bf16x8*)(sm + KF + ((size_t)(tt*2+0)*64 + lane)*16);
      bf16x8 Kt1 = *(const bf16x8*)(sm + KF + ((size_t)(tt*2+1)*64 + lane)*16);
      bf16x8 Vt0 = *(const bf16x8*)(sm + VF + ((size_t)(tt*2+0)*64 + lane)*16);
      bf16x8 Vt1 = *(const bf16x8*)(sm + VF + ((size_t)(tt*2+1)*64 + lane)*16);
      f32x16 D = zero16();
      D = MFMA32(Kt0, Qfr[sb][0], D);      // D[t][s] over c (pre-scaled)
      D = MFMA32(Kt1, Qfr[sb][1], D);
      u32 Wd[8];
      #pragma unroll
      for(int p=0;p<4;p++)
        #pragma unroll
        for(int hh=0;hh<2;hh++)
          Wd[p*2+hh] = cvtpk(exp2f(D[4*p+2*hh]), exp2f(D[4*p+2*hh+1]));
      union { u32 wu[4]; bf16x8 v; } pf0, pf1;
      #pragma unroll
      for(int hh=0;hh<2;hh++){
        v2i res = pl32swap(Wd[0+hh], Wd[2+hh]);
        pf0.wu[hh] = (u32)res[0]; pf0.wu[2+hh] = (u32)res[1];
        v2i res2 = pl32swap(Wd[4+hh], Wd[6+hh]);
        pf1.wu[hh] = (u32)res2[0]; pf1.wu[2+hh] = (u32)res2[1];
      }
      O = MFMA32(Vt0, pf0.v, O);
      O = MFMA32(Vt1, pf1.v, O);
    }
    // epilogue: gate from registers, paired uint2 stores to obuf
    const int stg = 2*w + sb;
    const int srow = n0 + stg*32 + j;
    u32* ob32 = (u32*)(obuf + (size_t)srow*CM + head*32);
    #pragma unroll
    for(int p=0;p<4;p++){
      u32 g0 = greg[sb][p*2+0], g1 = greg[sb][p*2+1];
      u32 w0 = cvtpk(O[4*p+0] * lo16f(g0), O[4*p+1] * hi16f(g0));
      u32 w1 = cvtpk(O[4*p+2] * lo16f(g1), O[4*p+3] * hi16f(g1));
      *(uint2*)(ob32 + 4*p + 2*gg) = make_uint2(w0, w1);
    }
  }
}

// --------------------------------------------------------------- outproj2 ----
// MFMA32, frag-ordered weights. 256 thr / 4 waves; wave w -> rows row0..row0+31.
__global__ __launch_bounds__(256,4) void outproj2(const u16* __restrict__ obuf,
      const u16* __restrict__ oWfh, const u16* __restrict__ oWfl,
      const float* __restrict__ ob, float* __restrict__ out){
  const int tid = threadIdx.x, w = tid>>6, lane = tid&63;
  const int gg = lane>>5, j = lane&31;
  const int row0 = blockIdx.x*128 + w*32;
  const u16* arow = obuf + (size_t)(row0 + j)*CM + gg*8;
  #pragma unroll 2
  for(int ct=0; ct<8; ct++){
    f32x16 acc = zero16();
    const u16* bh = oWfh + ((size_t)(ct*16)*64 + lane)*8;
    const u16* bl = oWfl + ((size_t)(ct*16)*64 + lane)*8;
    #pragma unroll
    for(int kc=0; kc<16; kc++){
      bf16x8 a = *(const bf16x8*)(arow + kc*16);
      acc = MFMA32(a, *(const bf16x8*)(bh + (size_t)kc*512), acc);
      acc = MFMA32(a, *(const bf16x8*)(bl + (size_t)kc*512), acc);
    }
    float bias = ob[ct*32 + j];
    #pragma unroll
    for(int reg=0; reg<16; reg++){
      int n = row0 + (reg&3) + 8*(reg>>2) + 4*gg;
      out[((size_t)(n & 511)*R_DIM + (n >> 9))*CM + ct*32 + j] = acc[reg] + bias;
    }
  }
}

// ------------------------------------------------------------------ host ----
extern "C" void kernel_launch(void* const* d_in, const int* in_sizes, int n_in,
                              void* d_out, int out_size, void* d_ws, size_t ws_size,
                              hipStream_t stream){
  const float* msa = (const float*)d_in[0];
  const float* lnw = (const float*)d_in[1];
  const float* lnb = (const float*)d_in[2];
  const float* Wq  = (const float*)d_in[3];
  const float* Wk  = (const float*)d_in[4];
  const float* Wv  = (const float*)d_in[5];
  const float* Wg  = (const float*)d_in[6];
  const float* oW  = (const float*)d_in[7];
  const float* ob  = (const float*)d_in[8];
  float* out = (float*)d_out;

  char* ws = (char*)d_ws;
  u16*   Wfrag  = (u16*)(ws);
  float* ball   = (float*)(ws + 524288);
  u16*   oWfh   = (u16*)(ws + 528384);
  u16*   oWfl   = (u16*)(ws + 659456);
  u16*   xhat   = (u16*)(ws + 790528);
  u16*   obuf   = (u16*)(ws + 101453824);

  (void)hipFuncSetAttribute((const void*)attn_fused4,
                      hipFuncAttributeMaxDynamicSharedMemorySize, ATTN_LDS);

  prep_w<<<dim3(1280), dim3(64), 0, stream>>>(lnw, lnb, Wq, Wk, Wv, Wg, oW,
                                              ball, Wfrag, oWfh, oWfl);
  ln_xhat<<<dim3(NROWS/32), dim3(256), 0, stream>>>(msa, xhat);
  attn_fused4<<<dim3(R_DIM*NH), dim3(512), ATTN_LDS, stream>>>(xhat, Wfrag, ball, obuf);
  outproj2<<<dim3(NROWS/128), dim3(256), 0, stream>>>(obuf, oWfh, oWfl, ob, out);
}

// Round 20
// 965.748 us; speedup vs baseline: 2.2407x; 1.0047x over previous
//
#include <hip/hip_runtime.h>
#include <hip/hip_bf16.h>

// MSAColumnAttention — R20: R19 frozen + tt-loop unroll 2->4 in attn phases 1/2.
// Rationale: R12's unroll-2 was the biggest post-R11 win (-42us, latency cover);
// (512,1) has reg headroom (demand ~160 of 256/wave band). Last in-structure
// lever; if null, R19/R20 is the converged configuration (~970us, 9.6x vs R0).
// Tripwire: WRITE_SIZE >> 120MB or occupancy < 20% => spill => R19 final.
//
// 32x32x16 bf16 MFMA layouts (R4/R6-verified):
//   A[m][k]: lane(gg,j)=gg*32+j holds row m=j, k=8gg+e ; B likewise (col n=j)
//   D[m][n]: lane(gg,j) holds col n=j, rows m=(reg&3)+8*(reg>>2)+4*gg
// Fragment construction: 8x cvt_pk + 4x permlane32_swap per D-tile (verified).
//
// ws layout (total 202,117,120 B):
//   Wfrag [8][4][16 kc][64 lane][8 bf16] @0 (512 KB) | ball [1024] f32 @524288
//   oWfh [8 mtile][16 kc][64 lane][8] bf16 @528384 | oWfl @659456
//   xhat [196608][256] bf16 @790528 | obuf [196608][256] bf16 @101453824

#define S_DIM 512
#define R_DIM 384
#define CM    256
#define NH    8
#define NROWS (S_DIM*R_DIM)

typedef unsigned short u16;
typedef unsigned int   u32;
typedef short bf16x8 __attribute__((ext_vector_type(8)));
typedef float f32x4  __attribute__((ext_vector_type(4)));
typedef float f32x16 __attribute__((ext_vector_type(16)));
typedef int   v2i    __attribute__((ext_vector_type(2)));

#define MFMA32(a,b,c) __builtin_amdgcn_mfma_f32_32x32x16_bf16((a),(b),(c),0,0,0)

__device__ __forceinline__ float lo16f(u32 u){ return __uint_as_float(u << 16); }
__device__ __forceinline__ float hi16f(u32 u){ return __uint_as_float(u & 0xffff0000u); }
__device__ __forceinline__ float b2f(u16 x){ return __uint_as_float(((u32)x) << 16); }
__device__ __forceinline__ u16 f2bf(float f){
  u32 u = __float_as_uint(f);
  return (u16)((u + 0x7fffu + ((u >> 16) & 1u)) >> 16);   // RNE
}
__device__ __forceinline__ u32 pk2(float a, float b){
  return (u32)f2bf(a) | ((u32)f2bf(b) << 16);
}
__device__ __forceinline__ u32 cvtpk(float a, float b){
  u32 d;
  asm("v_cvt_pk_bf16_f32 %0, %1, %2" : "=v"(d) : "v"(a), "v"(b));
  return d;
}
__device__ __forceinline__ v2i pl32swap(u32 a, u32 b){
  return __builtin_amdgcn_permlane32_swap((int)a, (int)b, false, false);
}
__device__ __forceinline__ f32x16 zero16(){
  f32x16 z;
  #pragma unroll
  for(int q=0;q<16;q++) z[q]=0.f;
  return z;
}

#define SC2 0.2550348653f   // (1/sqrt(32)) * log2(e), folded into K at prep (R9-proven)

// ---------------------------------------------------------------- prep_w ----
// blocks 0..1023 (h*128 + mat*32 + c): fold ln (and SC2 for K) into W row,
// write FRAG-ORDERED Wfrag[h][mat][kc][lane=gg*32+c][8] bf16; ball likewise.
// blocks 1024..1279: oW hi/lo split, FRAG-ORDERED oWfh/oWfl[mtile][kc][lane][8].
__global__ void prep_w(const float* __restrict__ lnw, const float* __restrict__ lnb,
                       const float* __restrict__ Wq, const float* __restrict__ Wk,
                       const float* __restrict__ Wv, const float* __restrict__ Wg,
                       const float* __restrict__ oW,
                       float* __restrict__ ball, u16* __restrict__ Wfrag,
                       u16* __restrict__ oWfh, u16* __restrict__ oWfl){
  int blk = blockIdx.x, t = threadIdx.x;
  // elements k(d) = 4t..4t+3 -> kc = t>>2, gg = (t>>1)&1, e0 = (t&1)*4
  int kc = t >> 2, gg = (t >> 1) & 1, e0 = (t & 1) * 4;
  if (blk < 1024){
    int h = blk >> 7, row = blk & 127, mat = row >> 5, c = row & 31;
    const float* Ws = (mat==0?Wq: mat==1?Wk: mat==2?Wv:Wg) + (size_t)(h*32+c)*CM;
    const float qs = (mat==1) ? SC2 : 1.f;   // fold softmax scale into K (f32, pre-round)
    float4 w4 = ((const float4*)Ws)[t];
    float4 l4 = ((const float4*)(lnw + (size_t)h*CM))[t];
    float4 b4 = ((const float4*)(lnb + (size_t)h*CM))[t];
    u16* dst = Wfrag + ((size_t)(((blk>>5)*16 + kc))*64 + gg*32 + c)*8 + e0;  // blk>>5 = h*4+mat
    *(uint2*)dst = make_uint2(pk2(qs*w4.x*l4.x, qs*w4.y*l4.y),
                              pk2(qs*w4.z*l4.z, qs*w4.w*l4.w));
    float p = w4.x*b4.x + w4.y*b4.y + w4.z*b4.z + w4.w*b4.w;
    #pragma unroll
    for(int off=32; off; off>>=1) p += __shfl_down(p, off);
    if(t==0) ball[blk] = qs*p;
  } else {
    int m = blk - 1024;
    float4 w4 = ((const float4*)(oW + (size_t)m*CM))[t];
    u16 h0=f2bf(w4.x), h1=f2bf(w4.y), h2=f2bf(w4.z), h3=f2bf(w4.w);
    u16 l0=f2bf(w4.x-b2f(h0)), l1=f2bf(w4.y-b2f(h1));
    u16 l2=f2bf(w4.z-b2f(h2)), l3=f2bf(w4.w-b2f(h3));
    size_t idx = ((size_t)(((m>>5)*16 + kc))*64 + gg*32 + (m&31))*8 + e0;
    *(uint2*)(oWfh + idx) = make_uint2((u32)h0|((u32)h1<<16), (u32)h2|((u32)h3<<16));
    *(uint2*)(oWfl + idx) = make_uint2((u32)l0|((u32)l1<<16), (u32)l2|((u32)l3<<16));
  }
}

// ---------------------------------------------------------------- ln_xhat ----
// 8 threads/row, 32 floats each, interleaved float4-chunk ownership (ch = c*8+p):
// 8 consecutive lanes -> 128B contiguous on load and store. Stats via 3 xor-shfls.
__global__ __launch_bounds__(256) void ln_xhat(const float* __restrict__ msa,
                                               u16* __restrict__ xhat){
  const int tid = threadIdx.x;
  const int n0 = blockIdx.x*32;
  const int i = tid >> 3, p = tid & 7;
  const int n = n0 + i, rr = n >> 9, s = n & 511;
  const float* src = msa + ((size_t)s*R_DIM + rr)*CM;
  float x[32]; float sum=0.f, sq=0.f;
  #pragma unroll
  for(int c=0;c<8;c++){
    float4 v = ((const float4*)src)[c*8 + p];
    x[c*4]=v.x; x[c*4+1]=v.y; x[c*4+2]=v.z; x[c*4+3]=v.w;
    sum += v.x+v.y+v.z+v.w;
    sq  += v.x*v.x + v.y*v.y + v.z*v.z + v.w*v.w;
  }
  sum += __shfl_xor(sum,1); sum += __shfl_xor(sum,2); sum += __shfl_xor(sum,4);
  sq  += __shfl_xor(sq,1);  sq  += __shfl_xor(sq,2);  sq  += __shfl_xor(sq,4);
  float mu = sum*(1.f/256.f);
  float rs = rsqrtf(sq*(1.f/256.f) - mu*mu + 1e-5f);
  uint2* dst = (uint2*)(xhat + (size_t)n*CM);
  #pragma unroll
  for(int c=0;c<8;c++)
    dst[c*8 + p] = make_uint2(pk2((x[c*4]-mu)*rs,   (x[c*4+1]-mu)*rs),
                              pk2((x[c*4+2]-mu)*rs, (x[c*4+3]-mu)*rs));
}

// --------------------------------------------------------------- attn_fused4 ----
// 512 thr / 8 waves, 1 block/CU (LDS-capped). Wave w owns s-tiles {2w, 2w+1}.
// proj: Wf from Wfrag (L2-hot); Q->regs, K/V->LDS, G->REGS.
// phase1: per-wave partial d (4-chain split, unroll 4) -> dred; reduce -> ivd.
// V-scale by ivd; phase2 (unroll 4): QK+exp+PV; epilogue paired uint2 stores.
#define KF    0
#define VF    32768
#define DRED  65536
#define ATTN_LDS 81920

__global__ __launch_bounds__(512,1) void attn_fused4(const u16* __restrict__ xhat,
      const u16* __restrict__ Wfrag, const float* __restrict__ ball,
      u16* __restrict__ obuf){
  extern __shared__ char sm[];
  const int bid = blockIdx.x;
  const int xcd = bid & 7, kk2 = bid >> 3;
  const int r = xcd*48 + (kk2 >> 3);     // 8 heads of one r consecutive on one XCD
  const int head = kk2 & 7;
  const int tid  = threadIdx.x;
  const int w    = tid >> 6;
  const int lane = tid & 63;
  const int gg = lane >> 5, j = lane & 31;
  const int n0 = r * 512;

  bf16x8 Qfr[2][2];   // own s-tiles' Q fragments (static indexing only)
  u32 greg[2][8];     // own s-tiles' gate words (bf16x2 each; static indexing only)

  // ================= proj =================
  {
    #pragma unroll
    for(int mat=0; mat<4; mat++){
      bf16x8 Wf[16];
      const u16* wsrc = Wfrag + ((size_t)((head*4+mat)*16)*64 + lane)*8;
      #pragma unroll
      for(int kc=0;kc<16;kc++) Wf[kc] = *(const bf16x8*)(wsrc + (size_t)kc*512);
      float bias16[16]; float biasv = 0.f;
      if (mat == 2) biasv = ball[head*128 + 64 + j];
      else {
        #pragma unroll
        for(int reg=0;reg<16;reg++)
          bias16[reg] = ball[head*128 + mat*32 + (reg&3) + 8*(reg>>2) + 4*gg];
      }
      #pragma unroll
      for(int st=0; st<2; st++){
        const int stg = 2*w + st;
        const u16* xr = xhat + ((size_t)(n0 + stg*32 + j))*CM + gg*8;
        f32x16 D = zero16();
        if (mat == 2){
          #pragma unroll
          for(int kc=0;kc<16;kc++) D = MFMA32(*(const bf16x8*)(xr + kc*16), Wf[kc], D);
        } else {
          #pragma unroll
          for(int kc=0;kc<16;kc++) D = MFMA32(Wf[kc], *(const bf16x8*)(xr + kc*16), D);
        }
        if (mat == 3){                     // G: sigmoid -> registers (no obuf trip)
          #pragma unroll
          for(int p=0;p<4;p++)
            #pragma unroll
            for(int hh=0;hh<2;hh++){
              float a = D[4*p+2*hh]   + bias16[4*p+2*hh];
              float b = D[4*p+2*hh+1] + bias16[4*p+2*hh+1];
              greg[st][p*2+hh] = cvtpk(1.f/(1.f + __expf(-a)), 1.f/(1.f + __expf(-b)));
            }
        } else {
          if (mat == 2){
            #pragma unroll
            for(int q=0;q<16;q++) D[q] += biasv;
          } else {
            #pragma unroll
            for(int q=0;q<16;q++) D[q] += bias16[q];
          }
          u32 Wd[8];
          #pragma unroll
          for(int p=0;p<4;p++)
            #pragma unroll
            for(int hh=0;hh<2;hh++)
              Wd[p*2+hh] = cvtpk(D[4*p+2*hh], D[4*p+2*hh+1]);
          u32 frag[2][4];
          #pragma unroll
          for(int T=0;T<2;T++)
            #pragma unroll
            for(int hh=0;hh<2;hh++){
              v2i res = pl32swap(Wd[4*T+hh], Wd[4*T+2+hh]);
              frag[T][hh] = (u32)res[0]; frag[T][2+hh] = (u32)res[1];
            }
          if (mat == 0){
            #pragma unroll
            for(int T=0;T<2;T++){
              union { u32 wu[4]; bf16x8 v; } u;
              u.wu[0]=frag[T][0]; u.wu[1]=frag[T][1]; u.wu[2]=frag[T][2]; u.wu[3]=frag[T][3];
              Qfr[st][T] = u.v;
            }
          } else {
            char* outbase = sm + (mat==1? KF : VF);
            #pragma unroll
            for(int T=0;T<2;T++)
              *(uint4*)(outbase + ((size_t)(stg*2+T)*64 + lane)*16) =
                  make_uint4(frag[T][0],frag[T][1],frag[T][2],frag[T][3]);
          }
        }
      }
    }
  }
  __syncthreads();

  // ================= phase 1: per-wave partial d (4 chains, unroll 4) =========
  {
    float* dred = (float*)(sm + DRED);
    #pragma unroll 4
    for(int tt=0; tt<16; tt++){
      bf16x8 Kt0 = *(const bf16x8*)(sm + KF + ((size_t)(tt*2+0)*64 + lane)*16);
      bf16x8 Kt1 = *(const bf16x8*)(sm + KF + ((size_t)(tt*2+1)*64 + lane)*16);
      float d0=0.f, d1=0.f, d2=0.f, d3=0.f;
      #pragma unroll
      for(int sb=0; sb<2; sb++){
        f32x16 D1 = zero16();
        D1 = MFMA32(Qfr[sb][0], Kt0, D1);   // D1[s][t] over c (K pre-scaled by SC2)
        D1 = MFMA32(Qfr[sb][1], Kt1, D1);
        #pragma unroll
        for(int q=0;q<16;q+=4){
          d0 += exp2f(D1[q]);   d1 += exp2f(D1[q+1]);
          d2 += exp2f(D1[q+2]); d3 += exp2f(D1[q+3]);
        }
      }
      float dp = (d0+d1)+(d2+d3);
      v2i rr = pl32swap(__float_as_uint(dp), __float_as_uint(dp));
      float tot = __uint_as_float((u32)rr[0]) + __uint_as_float((u32)rr[1]);
      if (lane < 32) dred[w*512 + tt*32 + j] = tot;
    }
  }
  __syncthreads();
  {
    float* dred = (float*)(sm + DRED);
    float s = 0.f;
    #pragma unroll
    for(int ww=0; ww<8; ww++) s += dred[ww*512 + tid];
    dred[tid] = 1.f / s;                    // ivd overlays row 0
  }
  __syncthreads();

  // ================= scale V-frags by ivd[t] =================
  {
    const float* ivd = (const float*)(sm + DRED);
    #pragma unroll
    for(int it=0; it<4; it++){
      int ch = tid + it*512;
      int t0 = (ch>>7)*32 + ((ch>>6)&1)*16 + ((ch>>5)&1)*8;
      u32* pw = (u32*)(sm + VF + (size_t)ch*16);
      uint4 v = *(uint4*)pw;
      u32 wv[4] = {v.x, v.y, v.z, v.w};
      u32 nw[4];
      #pragma unroll
      for(int rr2=0;rr2<4;rr2++){
        float lo = lo16f(wv[rr2]) * ivd[t0 + 2*rr2];
        float hi = hi16f(wv[rr2]) * ivd[t0 + 2*rr2 + 1];
        nw[rr2] = cvtpk(lo, hi);
      }
      *(uint4*)pw = make_uint4(nw[0],nw[1],nw[2],nw[3]);
    }
  }
  __syncthreads();

  // ================= phase 2 (unroll 4) + gated epilogue =================
  #pragma unroll
  for(int sb=0; sb<2; sb++){
    f32x16 O = zero16();
    #pragma unroll 4
    for(int tt=0; tt<16; tt++){
      bf16x8 Kt0 = *(const bf16x8*)(sm + KF + ((size_t)(tt*2+0)*64 + lane)*16);
      bf16x8 Kt1 = *(const bf16x8*)(sm + KF + ((size_t)(tt*2+1)*64 + lane)*16);
      bf16x8 Vt0 = *(const bf16x8*)(sm + VF + ((size_t)(tt*2+0)*64 + lane)*16);
      bf16x8 Vt1 = *(const bf16x8*)(sm + VF + ((size_t)(tt*2+1)*64 + lane)*16);
      f32x16 D = zero16();
      D = MFMA32(Kt0, Qfr[sb][0], D);      // D[t][s] over c (pre-scaled)
      D = MFMA32(Kt1, Qfr[sb][1], D);
      u32 Wd[8];
      #pragma unroll
      for(int p=0;p<4;p++)
        #pragma unroll
        for(int hh=0;hh<2;hh++)
          Wd[p*2+hh] = cvtpk(exp2f(D[4*p+2*hh]), exp2f(D[4*p+2*hh+1]));
      union { u32 wu[4]; bf16x8 v; } pf0, pf1;
      #pragma unroll
      for(int hh=0;hh<2;hh++){
        v2i res = pl32swap(Wd[0+hh], Wd[2+hh]);
        pf0.wu[hh] = (u32)res[0]; pf0.wu[2+hh] = (u32)res[1];
        v2i res2 = pl32swap(Wd[4+hh], Wd[6+hh]);
        pf1.wu[hh] = (u32)res2[0]; pf1.wu[2+hh] = (u32)res2[1];
      }
      O = MFMA32(Vt0, pf0.v, O);
      O = MFMA32(Vt1, pf1.v, O);
    }
    // epilogue: gate from registers, paired uint2 stores to obuf
    const int stg = 2*w + sb;
    const int srow = n0 + stg*32 + j;
    u32* ob32 = (u32*)(obuf + (size_t)srow*CM + head*32);
    #pragma unroll
    for(int p=0;p<4;p++){
      u32 g0 = greg[sb][p*2+0], g1 = greg[sb][p*2+1];
      u32 w0 = cvtpk(O[4*p+0] * lo16f(g0), O[4*p+1] * hi16f(g0));
      u32 w1 = cvtpk(O[4*p+2] * lo16f(g1), O[4*p+3] * hi16f(g1));
      *(uint2*)(ob32 + 4*p + 2*gg) = make_uint2(w0, w1);
    }
  }
}

// --------------------------------------------------------------- outproj2 ----
// MFMA32, frag-ordered weights. 256 thr / 4 waves; wave w -> rows row0..row0+31.
__global__ __launch_bounds__(256,4) void outproj2(const u16* __restrict__ obuf,
      const u16* __restrict__ oWfh, const u16* __restrict__ oWfl,
      const float* __restrict__ ob, float* __restrict__ out){
  const int tid = threadIdx.x, w = tid>>6, lane = tid&63;
  const int gg = lane>>5, j = lane&31;
  const int row0 = blockIdx.x*128 + w*32;
  const u16* arow = obuf + (size_t)(row0 + j)*CM + gg*8;
  #pragma unroll 2
  for(int ct=0; ct<8; ct++){
    f32x16 acc = zero16();
    const u16* bh = oWfh + ((size_t)(ct*16)*64 + lane)*8;
    const u16* bl = oWfl + ((size_t)(ct*16)*64 + lane)*8;
    #pragma unroll
    for(int kc=0; kc<16; kc++){
      bf16x8 a = *(const bf16x8*)(arow + kc*16);
      acc = MFMA32(a, *(const bf16x8*)(bh + (size_t)kc*512), acc);
      acc = MFMA32(a, *(const bf16x8*)(bl + (size_t)kc*512), acc);
    }
    float bias = ob[ct*32 + j];
    #pragma unroll
    for(int reg=0; reg<16; reg++){
      int n = row0 + (reg&3) + 8*(reg>>2) + 4*gg;
      out[((size_t)(n & 511)*R_DIM + (n >> 9))*CM + ct*32 + j] = acc[reg] + bias;
    }
  }
}

// ------------------------------------------------------------------ host ----
extern "C" void kernel_launch(void* const* d_in, const int* in_sizes, int n_in,
                              void* d_out, int out_size, void* d_ws, size_t ws_size,
                              hipStream_t stream){
  const float* msa = (const float*)d_in[0];
  const float* lnw = (const float*)d_in[1];
  const float* lnb = (const float*)d_in[2];
  const float* Wq  = (const float*)d_in[3];
  const float* Wk  = (const float*)d_in[4];
  const float* Wv  = (const float*)d_in[5];
  const float* Wg  = (const float*)d_in[6];
  const float* oW  = (const float*)d_in[7];
  const float* ob  = (const float*)d_in[8];
  float* out = (float*)d_out;

  char* ws = (char*)d_ws;
  u16*   Wfrag  = (u16*)(ws);
  float* ball   = (float*)(ws + 524288);
  u16*   oWfh   = (u16*)(ws + 528384);
  u16*   oWfl   = (u16*)(ws + 659456);
  u16*   xhat   = (u16*)(ws + 790528);
  u16*   obuf   = (u16*)(ws + 101453824);

  (void)hipFuncSetAttribute((const void*)attn_fused4,
                      hipFuncAttributeMaxDynamicSharedMemorySize, ATTN_LDS);

  prep_w<<<dim3(1280), dim3(64), 0, stream>>>(lnw, lnb, Wq, Wk, Wv, Wg, oW,
                                              ball, Wfrag, oWfh, oWfl);
  ln_xhat<<<dim3(NROWS/32), dim3(256), 0, stream>>>(msa, xhat);
  attn_fused4<<<dim3(R_DIM*NH), dim3(512), ATTN_LDS, stream>>>(xhat, Wfrag, ball, obuf);
  outproj2<<<dim3(NROWS/128), dim3(256), 0, stream>>>(obuf, oWfh, oWfl, ob, out);
}